// Round 16
// baseline (436.256 us; speedup 1.0000x reference)
//
#include <hip/hip_runtime.h>
#include <hip/hip_bf16.h>

typedef __hip_bfloat16 bf16;
#define DEVI __device__ __forceinline__

// Problem constants
static constexpr int BATCH = 8;
static constexpr int NPT   = 2048;
static constexpr int DMID  = 64;
static constexpr int DEMB  = 256;
static constexpr int NSA   = 4;
static constexpr long STRD = (long)DEMB * NPT;  // 524288
static constexpr long QKS  = (long)NPT * 512;   // per-batch stride of QKt
static constexpr long NN   = (long)NPT * NPT;   // 4194304

typedef __attribute__((ext_vector_type(4))) float f32x4;
typedef __attribute__((ext_vector_type(8))) short bf16x8v;

DEVI f32x4 MFMA16(bf16x8v a, bf16x8v b, f32x4 c) {
  return __builtin_amdgcn_mfma_f32_16x16x32_bf16(a, b, c, 0, 0, 0);
}

DEVI void gload16(const bf16* g, bf16* l) {
  __builtin_amdgcn_global_load_lds(
      (const __attribute__((address_space(1))) void*)g,
      (__attribute__((address_space(3))) void*)l, 16, 0, 0);
}

DEVI float waveReduceSum(float v) {
#pragma unroll
  for (int o = 32; o > 0; o >>= 1) v += __shfl_down(v, o, 64);
  return v;
}
DEVI float blockReduceSum(float v) {
  __shared__ float sm[4];
  int lane = threadIdx.x & 63, wid = threadIdx.x >> 6;
  __syncthreads();
  v = waveReduceSum(v);
  if (lane == 0) sm[wid] = v;
  __syncthreads();
  return sm[0] + sm[1] + sm[2] + sm[3];
}

// ---- fp32 -> bf16 convert ----
__global__ void k_cvt(const float* __restrict__ in, bf16* __restrict__ out, int n) {
  int i = blockIdx.x * 256 + threadIdx.x;
  if (i < n) out[i] = __float2bfloat16(in[i]);
}

// ---- concat-convert Wq,Wk -> WQKb [l][512][256] bf16 ----
__global__ void k_cvtqk(const float* __restrict__ wq, const float* __restrict__ wk,
                        bf16* __restrict__ o) {
  int idx = blockIdx.x * 256 + threadIdx.x;  // NSA*512*256
  int c = idx & 255;
  int r = (idx >> 8) & 511;
  int l = idx >> 17;
  float v = (r < 256) ? wq[((l << 8) + r) * 256 + c] : wk[((l << 8) + (r - 256)) * 256 + c];
  o[idx] = __float2bfloat16(v);
}

// ---- conv1: H1t[b][n][o] = sum_c x[b,n,c]*w1[o,c] + b1[o] ----
__global__ void k_conv1t(const float* __restrict__ x, const float* __restrict__ w1,
                         const float* __restrict__ b1, float* __restrict__ h1t) {
  long idx = (long)blockIdx.x * 256 + threadIdx.x;  // [b*n][o]
  int o = idx & 63;
  long bn = idx >> 6;
  const float* xp = x + bn * 3;
  h1t[idx] = b1[o] + xp[0] * w1[o * 3] + xp[1] * w1[o * 3 + 1] + xp[2] * w1[o * 3 + 2];
}

// ---- BN1 stats on H1t [16384][64] ----
__global__ __launch_bounds__(256) void k_bn1a(const float* __restrict__ h, float* __restrict__ pS,
                                              float* __restrict__ pS2) {
  int c = threadIdx.x & 63, rg = threadIdx.x >> 6;
  long r0 = (long)blockIdx.x * 128 + rg * 32;
  float s = 0.f, s2 = 0.f;
  for (int i = 0; i < 32; ++i) {
    float v = h[(r0 + i) * 64 + c];
    s += v; s2 += v * v;
  }
  __shared__ float smS[256], smS2[256];
  smS[threadIdx.x] = s; smS2[threadIdx.x] = s2;
  __syncthreads();
  if (threadIdx.x < 64) {
    float a = 0.f, b = 0.f;
#pragma unroll
    for (int g = 0; g < 4; ++g) { a += smS[g * 64 + c]; b += smS2[g * 64 + c]; }
    pS[blockIdx.x * 64 + c] = a;
    pS2[blockIdx.x * 64 + c] = b;
  }
}
__global__ void k_bn1b(const float* __restrict__ pS, const float* __restrict__ pS2,
                       const float* __restrict__ g, const float* __restrict__ be,
                       float* __restrict__ sa, float* __restrict__ sb) {
  int c = threadIdx.x;
  if (c >= 64) return;
  float s = 0.f, s2 = 0.f;
  for (int i = 0; i < 128; ++i) { s += pS[i * 64 + c]; s2 += pS2[i * 64 + c]; }
  const float inv = 1.0f / (BATCH * NPT);
  float m = s * inv, var = s2 * inv - m * m;
  float A = rsqrtf(var + 1e-5f) * g[c];
  sa[c] = A; sb[c] = be[c] - m * A;
}
__global__ void k_bn1apply(const float* __restrict__ h, const float* __restrict__ sa,
                           const float* __restrict__ sb, bf16* __restrict__ o) {
  long idx = (long)blockIdx.x * 256 + threadIdx.x;
  int c = idx & 63;
  float v = fmaf(h[idx], sa[c], sb[c]);
  o[idx] = __float2bfloat16(v > 0.f ? v : 0.f);
}

// ---- BN2 stats on Hn [16384][256] (per-column = per-channel) ----
__global__ __launch_bounds__(256) void k_bn2a(const float* __restrict__ h,
                                              float* __restrict__ pA, float* __restrict__ pB) {
  int c = threadIdx.x;
  long r0 = (long)blockIdx.x * 128;
  float s = 0.f, s2 = 0.f;
  for (int i = 0; i < 128; ++i) {
    float v = h[(r0 + i) * DEMB + c];
    s += v; s2 += v * v;
  }
  pA[blockIdx.x * DEMB + c] = s;
  pB[blockIdx.x * DEMB + c] = s2;
}
__global__ void k_bn2b(const float* __restrict__ pA, const float* __restrict__ pB,
                       const float* __restrict__ g, const float* __restrict__ be,
                       float* __restrict__ sa, float* __restrict__ sb) {
  int c = threadIdx.x;  // 256 threads
  float s = 0.f, s2 = 0.f;
  for (int i = 0; i < 128; ++i) { s += pA[i * DEMB + c]; s2 += pB[i * DEMB + c]; }
  const float inv = 1.0f / (BATCH * NPT);
  float m = s * inv, var = s2 * inv - m * m;
  float A = rsqrtf(var + 1e-5f) * g[c];
  sa[c] = A; sb[c] = be[c] - m * A;
}
// BN2 apply + ReLU: write Hn (f32 residual) and Htb (bf16 operand)
__global__ void k_bnapply2(float* __restrict__ hn, bf16* __restrict__ htb,
                           const float* __restrict__ sa, const float* __restrict__ sb) {
  long idx = (long)blockIdx.x * 256 + threadIdx.x;
  int c = idx & (DEMB - 1);
  float v = fmaf(hn[idx], sa[c], sb[c]);
  v = v > 0.f ? v : 0.f;
  hn[idx] = v;
  htb[idx] = __float2bfloat16(v);
}

// ---- MFMA GEMM, B^T form: C[M][N] = A[M][K] . B[N][K]^T ; 128x128 tile, BK=64 ----
// XOR-swizzled LDS (granule ^= row&7) on both staging-source and read.
// MODE 0: C bf16 = acc + fused column-softmax partials; 1-D grid, z = bid % nz (XCD-pin)
// MODE 1: C bf16 = acc
// MODE 2: C f32 = acc + bias[col]
template <int MODE>
__global__ __launch_bounds__(256) void k_mgemm(
    const bf16* __restrict__ A, long aStr, int ldA,
    const bf16* __restrict__ B, long bStr, int ldB,
    void* __restrict__ Cv, long cStr, int ldC,
    int K,
    const float* __restrict__ bias,
    float* __restrict__ PMo, float* __restrict__ PSo, int nz) {
  __shared__ __align__(16) bf16 sA[128 * 64];
  __shared__ __align__(16) bf16 sB[128 * 64];
  __shared__ float smx[4][64], ssx[4][64];
  int bx, by, bz;
  if constexpr (MODE == 0) {
    bz = blockIdx.x % nz;
    int t = blockIdx.x / nz;
    bx = t & 15;
    by = t >> 4;
  } else {
    bx = blockIdx.x; by = blockIdx.y; bz = blockIdx.z;
  }
  A += aStr * bz;
  B += bStr * bz;
  const int bm = by * 128, bn = bx * 128;
  const int tid = threadIdx.x;
  const int lane = tid & 63, wv = tid >> 6;
  const int wr = (wv >> 1) * 64, wc = (wv & 1) * 64;
  f32x4 acc[4][4] = {};

  for (int k0 = 0; k0 < K; k0 += 64) {
#pragma unroll
    for (int i = 0; i < 4; ++i) {
      int c = i * 256 + tid;
      int row = c >> 3, g = c & 7;
      int gs = (g ^ (row & 7)) * 8;
      gload16(A + (long)(bm + row) * ldA + k0 + gs, sA + c * 8);
      gload16(B + (long)(bn + row) * ldB + k0 + gs, sB + c * 8);
    }
    __syncthreads();
    bf16x8v af[4][2], bfr[4][2];
#pragma unroll
    for (int mi = 0; mi < 4; ++mi)
#pragma unroll
      for (int ks = 0; ks < 2; ++ks) {
        int rA = wr + mi * 16 + (lane & 15);
        int rB = wc + mi * 16 + (lane & 15);
        int g = ks * 4 + (lane >> 4);
        af[mi][ks]  = *(const bf16x8v*)&sA[rA * 64 + ((g ^ (rA & 7)) * 8)];
        bfr[mi][ks] = *(const bf16x8v*)&sB[rB * 64 + ((g ^ (rB & 7)) * 8)];
      }
#pragma unroll
    for (int ks = 0; ks < 2; ++ks)
#pragma unroll
      for (int mi = 0; mi < 4; ++mi)
#pragma unroll
        for (int ni = 0; ni < 4; ++ni)
          acc[mi][ni] = MFMA16(af[mi][ks], bfr[ni][ks], acc[mi][ni]);
    __syncthreads();
  }

  const int rb = (lane >> 4) * 4, cb = lane & 15;
  if constexpr (MODE == 0 || MODE == 1) {
    bf16* C = (bf16*)Cv + cStr * bz;
#pragma unroll
    for (int mi = 0; mi < 4; ++mi)
#pragma unroll
      for (int ni = 0; ni < 4; ++ni) {
        int r0 = bm + wr + mi * 16 + rb, c0 = bn + wc + ni * 16 + cb;
#pragma unroll
        for (int k = 0; k < 4; ++k)
          C[(long)(r0 + k) * ldC + c0] = __float2bfloat16(acc[mi][ni][k]);
      }
  } else {
    float* C = (float*)Cv + cStr * bz;
#pragma unroll
    for (int mi = 0; mi < 4; ++mi)
#pragma unroll
      for (int ni = 0; ni < 4; ++ni) {
        int r0 = bm + wr + mi * 16 + rb, c0 = bn + wc + ni * 16 + cb;
        float badd = bias[c0];
#pragma unroll
        for (int k = 0; k < 4; ++k) {
          int r = r0 + k;
          C[(long)r * ldC + c0] = acc[mi][ni][k] + badd;
        }
      }
  }

  if constexpr (MODE == 0) {
    // per-column (over this block's 128 rows) online-softmax partials (exact fp32)
    float cm[4], cs[4];
#pragma unroll
    for (int ni = 0; ni < 4; ++ni) {
      float m = -3.0e38f;
#pragma unroll
      for (int mi = 0; mi < 4; ++mi)
#pragma unroll
        for (int k = 0; k < 4; ++k) m = fmaxf(m, acc[mi][ni][k]);
      float s = 0.f;
#pragma unroll
      for (int mi = 0; mi < 4; ++mi)
#pragma unroll
        for (int k = 0; k < 4; ++k) s += __expf(acc[mi][ni][k] - m);
#pragma unroll
      for (int off = 16; off <= 32; off <<= 1) {
        float mo = __shfl_xor(m, off, 64);
        float so = __shfl_xor(s, off, 64);
        float M = fmaxf(m, mo);
        s = s * __expf(m - M) + so * __expf(mo - M);
        m = M;
      }
      cm[ni] = m; cs[ni] = s;
    }
    __syncthreads();  // LDS reads of K-loop complete; reuse smx/ssx safely
    if (lane < 16) {
#pragma unroll
      for (int ni = 0; ni < 4; ++ni) {
        smx[wv][ni * 16 + lane] = cm[ni];
        ssx[wv][ni * 16 + lane] = cs[ni];
      }
    }
    __syncthreads();
    if (tid < 128) {
      int half = tid >> 6, c64 = tid & 63;
      float m1 = smx[half][c64], s1 = ssx[half][c64];
      float m2 = smx[half + 2][c64], s2 = ssx[half + 2][c64];
      float M = fmaxf(m1, m2);
      float S = s1 * __expf(m1 - M) + s2 * __expf(m2 - M);
      long o = ((long)bz * 16 + by) * NPT + bn + half * 64 + c64;
      PMo[o] = M;
      PSo[o] = S;
    }
  }
}

// ---- combine 16 partials per column -> CM, CSi ----
__global__ void k_cms_fin(const float* __restrict__ PM, const float* __restrict__ PS,
                          float* __restrict__ CM, float* __restrict__ CSi) {
  long idx = (long)blockIdx.x * 256 + threadIdx.x;  // [G*NPT]
  long z = idx >> 11;
  int n = idx & (NPT - 1);
  const float* pm = PM + z * 16 * NPT + n;
  const float* ps = PS + z * 16 * NPT + n;
  float m = -3.0e38f;
#pragma unroll
  for (int y = 0; y < 16; ++y) m = fmaxf(m, pm[(long)y * NPT]);
  float s = 0.f;
#pragma unroll
  for (int y = 0; y < 16; ++y) s += ps[(long)y * NPT] * __expf(pm[(long)y * NPT] - m);
  CM[idx] = m;
  CSi[idx] = 1.0f / s;
}

// ---- fused normalize + rowsum + V.P GEMM (F bf16, 8 waves) ----
// Tile 256e x 64m; K = n = 0..2047. Grid 32*nz; z = bid % nz (XCD L2 pin).
// V TRIPLE-buffered and staged TWO steps ahead: per step issue
// {LOADF F(k+2) [oldest], STAGEV->sA[(k+2)%3] [4 loads]}, then EXPW(F(k+1)),
// MFMA(sA[k%3], sB[k&1]), then s_waitcnt vmcnt(5) lgkmcnt(0) + s_barrier:
// the 5 newest (this step's issues) stay in flight; stage(k+1) — issued a
// full step earlier — is forced complete. V L2 latency is fully covered.
// Epilogue: Hn[m][e] += acc*scl (f32) and Htb[m][e] = bf16(new).
__global__ __launch_bounds__(512) void k_vp(const bf16* __restrict__ F,
                                            const float* __restrict__ CM,
                                            const float* __restrict__ CSi,
                                            const bf16* __restrict__ V,
                                            float* __restrict__ Hn,
                                            bf16* __restrict__ Htb, int nz) {
  __shared__ __align__(16) bf16 sA[3][256 * 64];  // V tiles (triple-buffered)
  __shared__ __align__(16) bf16 sB[2][64 * 64];   // PT tiles (double-buffered)
  __shared__ float rsLds[64][8];
  __shared__ float Sv[64];
  __shared__ float smCM[NPT], smCS[NPT];
  const int z = blockIdx.x % nz;
  const int m0 = (blockIdx.x / nz) * 64;
  const int tid = threadIdx.x;
  const int lane = tid & 63, wv = tid >> 6;
  const int we = wv & 3;   // e-quarter 0..3 (64 rows)
  const int wm = wv >> 2;  // m-half 0..1 (32 cols)
  const int fr = tid >> 3; // F row 0..63
  const int fq = tid & 7;  // F col chunk 0..7
  const bf16* Vz = V + (long)z * STRD;
  const bf16* Frp = F + (long)z * NN + (long)(m0 + fr) * NPT + fq * 8;
  f32x4 acc[4][2] = {};
  float rs = 0.f;

  // one-time: stage CM/CSi for this batch into LDS (16 KB)
  {
    const float* cmz = CM + (long)z * NPT;
    const float* csz = CSi + (long)z * NPT;
#pragma unroll
    for (int i = 0; i < 4; ++i) {
      int idx = i * 512 + tid;
      smCM[idx] = cmz[idx];
      smCS[idx] = csz[idx];
    }
  }

#define LOADF(FREG, N0) FREG = *(const bf16x8v*)(Frp + ((N0) & 2047));

  // EXPW into pointer-addressed PT buffer; scales from LDS; accumulate rs
#define EXPW(PB, FREG, N0)                                                     \
  {                                                                            \
    float mv[8], cv[8];                                                        \
    *(float4*)&mv[0] = *(const float4*)&smCM[(N0) + fq * 8];                   \
    *(float4*)&mv[4] = *(const float4*)&smCM[(N0) + fq * 8 + 4];               \
    *(float4*)&cv[0] = *(const float4*)&smCS[(N0) + fq * 8];                   \
    *(float4*)&cv[4] = *(const float4*)&smCS[(N0) + fq * 8 + 4];               \
    bf16 tb[8];                                                                \
    _Pragma("unroll") for (int i = 0; i < 8; ++i) {                            \
      float fvi = __uint_as_float((unsigned)(unsigned short)FREG[i] << 16);    \
      float pv = __expf(fvi - mv[i]) * cv[i];                                  \
      rs += pv;                                                                \
      tb[i] = __float2bfloat16(pv);                                            \
    }                                                                          \
    *(bf16x8v*)&(PB)[fr * 64 + ((fq ^ (fr & 7)) * 8)] = *(bf16x8v*)tb;         \
  }

  // STAGEV: issue 4 global_load_lds of V column-chunk into pointer buffer
#define STAGEV(PA, N0)                                                         \
  _Pragma("unroll") for (int i = 0; i < 4; ++i) {                              \
    int c = i * 512 + tid;                                                     \
    int row = c >> 3, g = c & 7;                                               \
    gload16(Vz + (long)row * NPT + ((N0) & 2047) + ((g ^ (row & 7)) * 8),      \
            &(PA)[c * 8]);                                                     \
  }

  bf16* pa0 = &sA[0][0];
  bf16* pa1 = &sA[1][0];
  bf16* pa2 = &sA[2][0];
  bf16* pb0 = &sB[0][0];
  bf16* pb1 = &sB[1][0];

  // prologue: V(0)->pa0, V(1)->pa1; F(0) consumed into PT(0); F(1) in fvB.
  bf16x8v fvB, fnew;
  {
    bf16x8v f0;
    LOADF(f0, 0)
    LOADF(fvB, 64)
    STAGEV(pa0, 0)
    STAGEV(pa1, 64)
    __syncthreads();  // scales + V(0),V(1) + F regs all landed
    EXPW(pb0, f0, 0)
    __syncthreads();  // PT(0) visible
  }

  for (int sn = 0; sn < 32; ++sn) {
    const int nn1 = sn * 64 + 64;
    // issue F(k+2) first (oldest of this step), then V(k+2) stages
    LOADF(fnew, nn1 + 64)
    STAGEV(pa2, nn1 + 64)
    if (sn + 1 < 32) EXPW(pb1, fvB, nn1)
    // MFMA on sA[k%3]=pa0, sB[k&1]=pb0
    bf16x8v bfr[2][2];
#pragma unroll
    for (int ni = 0; ni < 2; ++ni)
#pragma unroll
      for (int ks = 0; ks < 2; ++ks) {
        int rB = wm * 32 + ni * 16 + (lane & 15);
        int g = ks * 4 + (lane >> 4);
        bfr[ni][ks] = *(const bf16x8v*)&pb0[rB * 64 + ((g ^ (rB & 7)) * 8)];
      }
#pragma unroll
    for (int mi = 0; mi < 4; ++mi)
#pragma unroll
      for (int ks = 0; ks < 2; ++ks) {
        int rA = we * 64 + mi * 16 + (lane & 15);
        int g = ks * 4 + (lane >> 4);
        bf16x8v af = *(const bf16x8v*)&pa0[rA * 64 + ((g ^ (rA & 7)) * 8)];
#pragma unroll
        for (int ni = 0; ni < 2; ++ni)
          acc[mi][ni] = MFMA16(af, bfr[ni][ks], acc[mi][ni]);
      }
    asm volatile("s_waitcnt vmcnt(5) lgkmcnt(0)" ::: "memory");
    __builtin_amdgcn_s_barrier();
    // rotate buffers & F registers
    bf16* t = pa0; pa0 = pa1; pa1 = pa2; pa2 = t;
    bf16* tb = pb0; pb0 = pb1; pb1 = tb;
    fvB = fnew;
  }
#undef STAGEV
#undef EXPW
#undef LOADF

  rsLds[fr][fq] = rs;
  __syncthreads();
  if (tid < 64) {
    float R = 0.f;
#pragma unroll
    for (int q = 0; q < 8; ++q) R += rsLds[tid][q];
    Sv[tid] = 1.0f / (1e-9f + R);
  }
  __syncthreads();

  float* Hz = Hn + (long)z * STRD;
  bf16* Hb = Htb + (long)z * STRD;
  const int rb = (lane >> 4) * 4, cb = lane & 15;
#pragma unroll
  for (int mi = 0; mi < 4; ++mi) {
    int e0 = we * 64 + mi * 16 + rb;
#pragma unroll
    for (int ni = 0; ni < 2; ++ni) {
      int c = wm * 32 + ni * 16 + cb;
      float scl = Sv[c];
      long base = (long)(m0 + c) * DEMB + e0;
      float4 h = *(const float4*)(Hz + base);
      float r0 = h.x + acc[mi][ni][0] * scl;
      float r1 = h.y + acc[mi][ni][1] * scl;
      float r2 = h.z + acc[mi][ni][2] * scl;
      float r3 = h.w + acc[mi][ni][3] * scl;
      *(float4*)(Hz + base) = float4{r0, r1, r2, r3};
      bf16 hb[4] = {__float2bfloat16(r0), __float2bfloat16(r1),
                    __float2bfloat16(r2), __float2bfloat16(r3)};
      *(uint2*)(Hb + base) = *(uint2*)hb;
    }
  }
}

// ---- pooled[b*n] = row mean of Hn [16384][256] (one wave per row) ----
__global__ void k_pool(const float* __restrict__ Hn, float* __restrict__ pooled) {
  int row = blockIdx.x * 4 + (threadIdx.x >> 6);
  int lane = threadIdx.x & 63;
  float4 v = *(const float4*)(Hn + (long)row * DEMB + lane * 4);
  float s = v.x + v.y + v.z + v.w;
  s = waveReduceSum(s);
  if (lane == 0) pooled[row] = s * (1.0f / DEMB);
}

// ---- fc1: one block per output row j; w row read ONCE, all 8 batches ----
__global__ __launch_bounds__(256) void k_fc1(const float* __restrict__ pooled,
                                             const float* __restrict__ w, const float* __restrict__ bias,
                                             float* __restrict__ f) {
  int j = blockIdx.x;
  const float* wr = w + (long)j * NPT;
  int n0 = threadIdx.x * 8;
  float wl[8];
  *(float4*)&wl[0] = *(const float4*)(wr + n0);
  *(float4*)&wl[4] = *(const float4*)(wr + n0 + 4);
  float part[8];
#pragma unroll
  for (int b = 0; b < 8; ++b) {
    const float* pp = pooled + (long)b * NPT + n0;
    float4 p0 = *(const float4*)pp, p1 = *(const float4*)(pp + 4);
    part[b] = wl[0] * p0.x + wl[1] * p0.y + wl[2] * p0.z + wl[3] * p0.w +
              wl[4] * p1.x + wl[5] * p1.y + wl[6] * p1.z + wl[7] * p1.w;
  }
#pragma unroll
  for (int b = 0; b < 8; ++b) {
    float s = blockReduceSum(part[b]);
    if (threadIdx.x == 0) {
      s += bias[j];
      f[(long)b * NPT + j] = s > 0.f ? s : 0.f;
    }
  }
}

// ---- fc2 ----
__global__ __launch_bounds__(256) void k_fc2(const float* __restrict__ f,
                                             const float* __restrict__ w, const float* __restrict__ bias,
                                             float* __restrict__ out) {
  int b = blockIdx.x;
  float s = 0.f;
  for (int j = threadIdx.x; j < NPT; j += 256) s += f[(long)b * NPT + j] * w[j];
  s = blockReduceSum(s);
  if (threadIdx.x == 0) out[b] = s + bias[0];
}

extern "C" void kernel_launch(void* const* d_in, const int* in_sizes, int n_in,
                              void* d_out, int out_size, void* d_ws, size_t ws_size,
                              hipStream_t stream) {
  const float* X    = (const float*)d_in[0];
  const float* W1   = (const float*)d_in[1];
  const float* B1   = (const float*)d_in[2];
  const float* G1   = (const float*)d_in[3];
  const float* BE1  = (const float*)d_in[4];
  const float* W2   = (const float*)d_in[5];
  const float* B2   = (const float*)d_in[6];
  const float* G2   = (const float*)d_in[7];
  const float* BE2  = (const float*)d_in[8];
  const float* WQ   = (const float*)d_in[9];
  const float* WK   = (const float*)d_in[10];
  const float* WV   = (const float*)d_in[11];
  const float* FC1W = (const float*)d_in[12];
  const float* FC1B = (const float*)d_in[13];
  const float* FC2W = (const float*)d_in[14];
  const float* FC2B = (const float*)d_in[15];
  float* OUT = (float*)d_out;

  // ---- workspace carve-out ----
  char* p = (char*)d_ws;
  auto alloc = [&](size_t bytes) -> char* {
    char* r = p;
    p += (bytes + 255) & ~(size_t)255;
    return r;
  };
  float* H1t  = (float*)alloc((size_t)BATCH * NPT * DMID * 4);
  bf16*  H1tb = (bf16*)alloc((size_t)BATCH * NPT * DMID * 2);
  float* Hn   = (float*)alloc((size_t)BATCH * STRD * 4);   // [b*n][256] f32
  bf16*  Htb  = (bf16*)alloc((size_t)BATCH * STRD * 2);    // [b*n][256] bf16
  bf16*  QKt  = (bf16*)alloc((size_t)BATCH * QKS * 2);     // [b][n][512]
  bf16*  Vb   = (bf16*)alloc((size_t)BATCH * STRD * 2);    // [b][e][n]
  bf16*  W2b  = (bf16*)alloc((size_t)DEMB * DMID * 2);
  bf16*  WQKb = (bf16*)alloc((size_t)NSA * 512 * DEMB * 2);
  bf16*  WVb  = (bf16*)alloc((size_t)NSA * DEMB * DEMB * 2);
  float* pS   = (float*)alloc(128 * 64 * 4);
  float* pS2  = (float*)alloc(128 * 64 * 4);
  float* pA2  = (float*)alloc(128 * DEMB * 4);
  float* pB2  = (float*)alloc(128 * DEMB * 4);
  float* sa1  = (float*)alloc(64 * 4);
  float* sb1  = (float*)alloc(64 * 4);
  float* sa2  = (float*)alloc(256 * 4);
  float* sb2  = (float*)alloc(256 * 4);
  float* CM   = (float*)alloc((size_t)BATCH * NPT * 4);
  float* CSi  = (float*)alloc((size_t)BATCH * NPT * 4);
  float* PM   = (float*)alloc((size_t)BATCH * 16 * NPT * 4);
  float* PSm  = (float*)alloc((size_t)BATCH * 16 * NPT * 4);
  float* POOL = (float*)alloc((size_t)BATCH * NPT * 4);
  float* FH   = (float*)alloc((size_t)BATCH * NPT * 4);
  size_t used = (size_t)(p - (char*)d_ws);
  const size_t per_g = (size_t)NN * 2;  // F bf16 (8MB per batch)
  int G = 8;
  while (G > 1 && used + (size_t)G * per_g + 1024 > ws_size) G >>= 1;
  bf16* F = (bf16*)alloc((size_t)G * NN * 2);

  // ---- weight converts ----
  k_cvt<<<(DEMB * DMID + 255) / 256, 256, 0, stream>>>(W2, W2b, DEMB * DMID);
  int nqk = NSA * 512 * DEMB;
  k_cvtqk<<<nqk / 256, 256, 0, stream>>>(WQ, WK, WQKb);
  int nw = NSA * DEMB * DEMB;
  k_cvt<<<(nw + 255) / 256, 256, 0, stream>>>(WV, WVb, nw);

  // ---- conv1 + BN1 + ReLU (-> H1tb bf16 [b*n][64]) ----
  long szh1 = (long)BATCH * NPT * DMID;
  k_conv1t<<<(int)(szh1 / 256), 256, 0, stream>>>(X, W1, B1, H1t);
  k_bn1a<<<128, 256, 0, stream>>>(H1t, pS, pS2);
  k_bn1b<<<1, 64, 0, stream>>>(pS, pS2, G1, BE1, sa1, sb1);
  k_bn1apply<<<(int)(szh1 / 256), 256, 0, stream>>>(H1t, sa1, sb1, H1tb);

  // ---- conv2 (MFMA, [n][e] layout) + BN2 + ReLU -> Hn f32 + Htb bf16 ----
  k_mgemm<2><<<dim3(2, 128, 1), 256, 0, stream>>>(H1tb, 0, DMID, W2b, 0, DMID,
                                                  Hn, 0, DEMB, DMID, B2, nullptr, nullptr, 0);
  k_bn2a<<<128, 256, 0, stream>>>(Hn, pA2, pB2);
  k_bn2b<<<1, 256, 0, stream>>>(pA2, pB2, G2, BE2, sa2, sb2);
  k_bnapply2<<<(int)(BATCH * STRD / 256), 256, 0, stream>>>(Hn, Htb, sa2, sb2);

  // ---- SA layers (no transpose needed; Htb maintained by k_vp epilogue) ----
  for (int l = 0; l < NSA; ++l) {
    // QKt[n][0..511] = Htb . [Wq;Wk]^T  : A=Htb (M=2048/b), B=WQK (N=512)
    k_mgemm<1><<<dim3(4, 16, 8), 256, 0, stream>>>(Htb, STRD, DEMB, WQKb + (long)l * 512 * DEMB, 0, DEMB,
                                                   QKt, QKS, 512, DEMB, nullptr, nullptr, nullptr, 0);
    // V[e][n] : A=Wv (M=256), B=Htb (N=2048)
    k_mgemm<1><<<dim3(16, 2, 8), 256, 0, stream>>>(WVb + (long)l * DEMB * DEMB, 0, DEMB, Htb, STRD, DEMB,
                                                   Vb, STRD, NPT, DEMB, nullptr, nullptr, nullptr, 0);
    for (int b0 = 0; b0 < BATCH; b0 += G) {
      // F[m][n] = sum_a Kt[m][a] Qt[n][a] (= E^T), bf16 + fused exact column stats
      k_mgemm<0><<<dim3(256 * G), 256, 0, stream>>>(QKt + 256 + b0 * QKS, QKS, 512,
                                                    QKt + b0 * QKS, QKS, 512,
                                                    F, NN, NPT, DEMB, nullptr, PM, PSm, G);
      k_cms_fin<<<G * NPT / 256, 256, 0, stream>>>(PM, PSm, CM, CSi);
      // Hn[m][e] += S[m] * sum_n V[e][n] PT[m][n]; Htb = bf16(Hn)
      k_vp<<<dim3(32 * G), 512, 0, stream>>>(F, CM, CSi, Vb + b0 * STRD,
                                             Hn + b0 * STRD, Htb + b0 * STRD, G);
    }
  }

  // ---- head ----
  k_pool<<<(BATCH * NPT) / 4, 256, 0, stream>>>(Hn, POOL);
  k_fc1<<<NPT, 256, 0, stream>>>(POOL, FC1W, FC1B, FH);
  k_fc2<<<BATCH, 256, 0, stream>>>(FH, FC2W, FC2B, OUT);
}

// Round 17
// 435.371 us; speedup vs baseline: 1.0020x; 1.0020x over previous
//
#include <hip/hip_runtime.h>
#include <hip/hip_bf16.h>

typedef __hip_bfloat16 bf16;
#define DEVI __device__ __forceinline__

// Problem constants
static constexpr int BATCH = 8;
static constexpr int NPT   = 2048;
static constexpr int DMID  = 64;
static constexpr int DEMB  = 256;
static constexpr int NSA   = 4;
static constexpr long STRD = (long)DEMB * NPT;  // 524288
static constexpr long QKS  = (long)NPT * 512;   // per-batch stride of QKt
static constexpr long NN   = (long)NPT * NPT;   // 4194304

typedef __attribute__((ext_vector_type(4))) float f32x4;
typedef __attribute__((ext_vector_type(8))) short bf16x8v;

DEVI f32x4 MFMA16(bf16x8v a, bf16x8v b, f32x4 c) {
  return __builtin_amdgcn_mfma_f32_16x16x32_bf16(a, b, c, 0, 0, 0);
}

DEVI void gload16(const bf16* g, bf16* l) {
  __builtin_amdgcn_global_load_lds(
      (const __attribute__((address_space(1))) void*)g,
      (__attribute__((address_space(3))) void*)l, 16, 0, 0);
}

DEVI float waveReduceSum(float v) {
#pragma unroll
  for (int o = 32; o > 0; o >>= 1) v += __shfl_down(v, o, 64);
  return v;
}
DEVI float blockReduceSum(float v) {
  __shared__ float sm[4];
  int lane = threadIdx.x & 63, wid = threadIdx.x >> 6;
  __syncthreads();
  v = waveReduceSum(v);
  if (lane == 0) sm[wid] = v;
  __syncthreads();
  return sm[0] + sm[1] + sm[2] + sm[3];
}

// ---- fp32 -> bf16 convert ----
__global__ void k_cvt(const float* __restrict__ in, bf16* __restrict__ out, int n) {
  int i = blockIdx.x * 256 + threadIdx.x;
  if (i < n) out[i] = __float2bfloat16(in[i]);
}

// ---- concat-convert Wq,Wk -> WQKb [l][512][256] bf16 ----
__global__ void k_cvtqk(const float* __restrict__ wq, const float* __restrict__ wk,
                        bf16* __restrict__ o) {
  int idx = blockIdx.x * 256 + threadIdx.x;  // NSA*512*256
  int c = idx & 255;
  int r = (idx >> 8) & 511;
  int l = idx >> 17;
  float v = (r < 256) ? wq[((l << 8) + r) * 256 + c] : wk[((l << 8) + (r - 256)) * 256 + c];
  o[idx] = __float2bfloat16(v);
}

// ---- conv1: H1t[b][n][o] = sum_c x[b,n,c]*w1[o,c] + b1[o] ----
__global__ void k_conv1t(const float* __restrict__ x, const float* __restrict__ w1,
                         const float* __restrict__ b1, float* __restrict__ h1t) {
  long idx = (long)blockIdx.x * 256 + threadIdx.x;  // [b*n][o]
  int o = idx & 63;
  long bn = idx >> 6;
  const float* xp = x + bn * 3;
  h1t[idx] = b1[o] + xp[0] * w1[o * 3] + xp[1] * w1[o * 3 + 1] + xp[2] * w1[o * 3 + 2];
}

// ---- BN1 stats on H1t [16384][64] ----
__global__ __launch_bounds__(256) void k_bn1a(const float* __restrict__ h, float* __restrict__ pS,
                                              float* __restrict__ pS2) {
  int c = threadIdx.x & 63, rg = threadIdx.x >> 6;
  long r0 = (long)blockIdx.x * 128 + rg * 32;
  float s = 0.f, s2 = 0.f;
  for (int i = 0; i < 32; ++i) {
    float v = h[(r0 + i) * 64 + c];
    s += v; s2 += v * v;
  }
  __shared__ float smS[256], smS2[256];
  smS[threadIdx.x] = s; smS2[threadIdx.x] = s2;
  __syncthreads();
  if (threadIdx.x < 64) {
    float a = 0.f, b = 0.f;
#pragma unroll
    for (int g = 0; g < 4; ++g) { a += smS[g * 64 + c]; b += smS2[g * 64 + c]; }
    pS[blockIdx.x * 64 + c] = a;
    pS2[blockIdx.x * 64 + c] = b;
  }
}
__global__ void k_bn1b(const float* __restrict__ pS, const float* __restrict__ pS2,
                       const float* __restrict__ g, const float* __restrict__ be,
                       float* __restrict__ sa, float* __restrict__ sb) {
  int c = threadIdx.x;
  if (c >= 64) return;
  float s = 0.f, s2 = 0.f;
  for (int i = 0; i < 128; ++i) { s += pS[i * 64 + c]; s2 += pS2[i * 64 + c]; }
  const float inv = 1.0f / (BATCH * NPT);
  float m = s * inv, var = s2 * inv - m * m;
  float A = rsqrtf(var + 1e-5f) * g[c];
  sa[c] = A; sb[c] = be[c] - m * A;
}
__global__ void k_bn1apply(const float* __restrict__ h, const float* __restrict__ sa,
                           const float* __restrict__ sb, bf16* __restrict__ o) {
  long idx = (long)blockIdx.x * 256 + threadIdx.x;
  int c = idx & 63;
  float v = fmaf(h[idx], sa[c], sb[c]);
  o[idx] = __float2bfloat16(v > 0.f ? v : 0.f);
}

// ---- BN2 stats on Hn [16384][256] (per-column = per-channel) ----
__global__ __launch_bounds__(256) void k_bn2a(const float* __restrict__ h,
                                              float* __restrict__ pA, float* __restrict__ pB) {
  int c = threadIdx.x;
  long r0 = (long)blockIdx.x * 128;
  float s = 0.f, s2 = 0.f;
  for (int i = 0; i < 128; ++i) {
    float v = h[(r0 + i) * DEMB + c];
    s += v; s2 += v * v;
  }
  pA[blockIdx.x * DEMB + c] = s;
  pB[blockIdx.x * DEMB + c] = s2;
}
__global__ void k_bn2b(const float* __restrict__ pA, const float* __restrict__ pB,
                       const float* __restrict__ g, const float* __restrict__ be,
                       float* __restrict__ sa, float* __restrict__ sb) {
  int c = threadIdx.x;  // 256 threads
  float s = 0.f, s2 = 0.f;
  for (int i = 0; i < 128; ++i) { s += pA[i * DEMB + c]; s2 += pB[i * DEMB + c]; }
  const float inv = 1.0f / (BATCH * NPT);
  float m = s * inv, var = s2 * inv - m * m;
  float A = rsqrtf(var + 1e-5f) * g[c];
  sa[c] = A; sb[c] = be[c] - m * A;
}
// BN2 apply + ReLU: write Hn (f32 residual) and Htb (bf16 operand)
__global__ void k_bnapply2(float* __restrict__ hn, bf16* __restrict__ htb,
                           const float* __restrict__ sa, const float* __restrict__ sb) {
  long idx = (long)blockIdx.x * 256 + threadIdx.x;
  int c = idx & (DEMB - 1);
  float v = fmaf(hn[idx], sa[c], sb[c]);
  v = v > 0.f ? v : 0.f;
  hn[idx] = v;
  htb[idx] = __float2bfloat16(v);
}

// ---- MFMA GEMM, B^T form: C[M][N] = A[M][K] . B[N][K]^T ; 128x128 tile, BK=64 ----
// XOR-swizzled LDS (granule ^= row&7) on both staging-source and read.
// nz > 0: 1-D grid, bz = bid % nz (XCD-pin), bx = t % gx, by = t / gx.
// MODE 0: C bf16 = acc + fused column-softmax partials (PM/PS)
// MODE 1: C bf16 = acc
// MODE 2: C f32 = acc + bias[col]
template <int MODE>
__global__ __launch_bounds__(256) void k_mgemm(
    const bf16* __restrict__ A, long aStr, int ldA,
    const bf16* __restrict__ B, long bStr, int ldB,
    void* __restrict__ Cv, long cStr, int ldC,
    int K,
    const float* __restrict__ bias,
    float* __restrict__ PMo, float* __restrict__ PSo, int nz, int gx) {
  __shared__ __align__(16) bf16 sA[128 * 64];
  __shared__ __align__(16) bf16 sB[128 * 64];
  __shared__ float smx[4][64], ssx[4][64];
  int bx, by, bz;
  if (nz > 0) {
    bz = blockIdx.x % nz;
    int t = blockIdx.x / nz;
    bx = t % gx;
    by = t / gx;
  } else {
    bx = blockIdx.x; by = blockIdx.y; bz = blockIdx.z;
  }
  A += aStr * bz;
  B += bStr * bz;
  const int bm = by * 128, bn = bx * 128;
  const int tid = threadIdx.x;
  const int lane = tid & 63, wv = tid >> 6;
  const int wr = (wv >> 1) * 64, wc = (wv & 1) * 64;
  f32x4 acc[4][4] = {};

  for (int k0 = 0; k0 < K; k0 += 64) {
#pragma unroll
    for (int i = 0; i < 4; ++i) {
      int c = i * 256 + tid;
      int row = c >> 3, g = c & 7;
      int gs = (g ^ (row & 7)) * 8;
      gload16(A + (long)(bm + row) * ldA + k0 + gs, sA + c * 8);
      gload16(B + (long)(bn + row) * ldB + k0 + gs, sB + c * 8);
    }
    __syncthreads();
    bf16x8v af[4][2], bfr[4][2];
#pragma unroll
    for (int mi = 0; mi < 4; ++mi)
#pragma unroll
      for (int ks = 0; ks < 2; ++ks) {
        int rA = wr + mi * 16 + (lane & 15);
        int rB = wc + mi * 16 + (lane & 15);
        int g = ks * 4 + (lane >> 4);
        af[mi][ks]  = *(const bf16x8v*)&sA[rA * 64 + ((g ^ (rA & 7)) * 8)];
        bfr[mi][ks] = *(const bf16x8v*)&sB[rB * 64 + ((g ^ (rB & 7)) * 8)];
      }
#pragma unroll
    for (int ks = 0; ks < 2; ++ks)
#pragma unroll
      for (int mi = 0; mi < 4; ++mi)
#pragma unroll
        for (int ni = 0; ni < 4; ++ni)
          acc[mi][ni] = MFMA16(af[mi][ks], bfr[ni][ks], acc[mi][ni]);
    __syncthreads();
  }

  const int rb = (lane >> 4) * 4, cb = lane & 15;
  if constexpr (MODE == 0 || MODE == 1) {
    bf16* C = (bf16*)Cv + cStr * bz;
#pragma unroll
    for (int mi = 0; mi < 4; ++mi)
#pragma unroll
      for (int ni = 0; ni < 4; ++ni) {
        int r0 = bm + wr + mi * 16 + rb, c0 = bn + wc + ni * 16 + cb;
#pragma unroll
        for (int k = 0; k < 4; ++k)
          C[(long)(r0 + k) * ldC + c0] = __float2bfloat16(acc[mi][ni][k]);
      }
  } else {
    float* C = (float*)Cv + cStr * bz;
#pragma unroll
    for (int mi = 0; mi < 4; ++mi)
#pragma unroll
      for (int ni = 0; ni < 4; ++ni) {
        int r0 = bm + wr + mi * 16 + rb, c0 = bn + wc + ni * 16 + cb;
        float badd = bias[c0];
#pragma unroll
        for (int k = 0; k < 4; ++k) {
          int r = r0 + k;
          C[(long)r * ldC + c0] = acc[mi][ni][k] + badd;
        }
      }
  }

  if constexpr (MODE == 0) {
    // per-column (over this block's 128 rows) online-softmax partials (exact fp32)
    float cm[4], cs[4];
#pragma unroll
    for (int ni = 0; ni < 4; ++ni) {
      float m = -3.0e38f;
#pragma unroll
      for (int mi = 0; mi < 4; ++mi)
#pragma unroll
        for (int k = 0; k < 4; ++k) m = fmaxf(m, acc[mi][ni][k]);
      float s = 0.f;
#pragma unroll
      for (int mi = 0; mi < 4; ++mi)
#pragma unroll
        for (int k = 0; k < 4; ++k) s += __expf(acc[mi][ni][k] - m);
#pragma unroll
      for (int off = 16; off <= 32; off <<= 1) {
        float mo = __shfl_xor(m, off, 64);
        float so = __shfl_xor(s, off, 64);
        float M = fmaxf(m, mo);
        s = s * __expf(m - M) + so * __expf(mo - M);
        m = M;
      }
      cm[ni] = m; cs[ni] = s;
    }
    __syncthreads();  // LDS reads of K-loop complete; reuse smx/ssx safely
    if (lane < 16) {
#pragma unroll
      for (int ni = 0; ni < 4; ++ni) {
        smx[wv][ni * 16 + lane] = cm[ni];
        ssx[wv][ni * 16 + lane] = cs[ni];
      }
    }
    __syncthreads();
    if (tid < 128) {
      int half = tid >> 6, c64 = tid & 63;
      float m1 = smx[half][c64], s1 = ssx[half][c64];
      float m2 = smx[half + 2][c64], s2 = ssx[half + 2][c64];
      float M = fmaxf(m1, m2);
      float S = s1 * __expf(m1 - M) + s2 * __expf(m2 - M);
      long o = ((long)bz * 16 + by) * NPT + bn + half * 64 + c64;
      PMo[o] = M;
      PSo[o] = S;
    }
  }
}

// ---- combine 16 partials per column -> CM, CSi ----
__global__ void k_cms_fin(const float* __restrict__ PM, const float* __restrict__ PS,
                          float* __restrict__ CM, float* __restrict__ CSi) {
  long idx = (long)blockIdx.x * 256 + threadIdx.x;  // [G*NPT]
  long z = idx >> 11;
  int n = idx & (NPT - 1);
  const float* pm = PM + z * 16 * NPT + n;
  const float* ps = PS + z * 16 * NPT + n;
  float m = -3.0e38f;
#pragma unroll
  for (int y = 0; y < 16; ++y) m = fmaxf(m, pm[(long)y * NPT]);
  float s = 0.f;
#pragma unroll
  for (int y = 0; y < 16; ++y) s += ps[(long)y * NPT] * __expf(pm[(long)y * NPT] - m);
  CM[idx] = m;
  CSi[idx] = 1.0f / s;
}

// ---- fused normalize + rowsum + V.P GEMM (F bf16, 2-phase dbuf, 8 waves) ----
// Per block: e = 0..255 (M), m in [m0, m0+64) (N), K = n = 0..2047.
// 512 threads = 8 waves arranged 4(e) x 2(m); tile 256e x 64m.
// 1-D grid 32*nz; z = bid % nz pins each batch's V to one XCD's L2.
// Epilogue: Hn[m][e] += acc*scl (f32 residual, [n][e] layout) AND
// Htb[m][e] = bf16(new) — fuses the next layer's operand convert.
// Per-step sync: counted s_waitcnt vmcnt(1)+lgkmcnt(0)+s_barrier; issue order
// STAGEV(4) then LOADF(1) keeps the F prefetch in flight across the barrier.
__global__ __launch_bounds__(512) void k_vp(const bf16* __restrict__ F,
                                            const float* __restrict__ CM,
                                            const float* __restrict__ CSi,
                                            const bf16* __restrict__ V,
                                            float* __restrict__ Hn,
                                            bf16* __restrict__ Htb, int nz) {
  __shared__ __align__(16) bf16 sA[2][256 * 64];  // V tiles (double-buffered)
  __shared__ __align__(16) bf16 sB[2][64 * 64];   // PT tiles (double-buffered)
  __shared__ float rsLds[64][8];
  __shared__ float Sv[64];
  __shared__ float smCM[NPT], smCS[NPT];
  const int z = blockIdx.x % nz;
  const int m0 = (blockIdx.x / nz) * 64;
  const int tid = threadIdx.x;
  const int lane = tid & 63, wv = tid >> 6;
  const int we = wv & 3;   // e-quarter 0..3 (64 rows)
  const int wm = wv >> 2;  // m-half 0..1 (32 cols)
  const int fr = tid >> 3; // F row 0..63
  const int fq = tid & 7;  // F col chunk 0..7
  const bf16* Vz = V + (long)z * STRD;
  const bf16* Frp = F + (long)z * NN + (long)(m0 + fr) * NPT + fq * 8;
  f32x4 acc[4][2] = {};
  float rs = 0.f;
  bf16x8v fvA, fvB;

  // one-time: stage CM/CSi for this batch into LDS (16 KB)
  {
    const float* cmz = CM + (long)z * NPT;
    const float* csz = CSi + (long)z * NPT;
#pragma unroll
    for (int i = 0; i < 4; ++i) {
      int idx = i * 512 + tid;
      smCM[idx] = cmz[idx];
      smCS[idx] = csz[idx];
    }
  }

#define LOADF(FREG, N0) FREG = *(const bf16x8v*)(Frp + ((N0) & 2047));

#define EXPW(BUF, FREG, N0)                                                    \
  {                                                                            \
    float mv[8], cv[8];                                                        \
    *(float4*)&mv[0] = *(const float4*)&smCM[(N0) + fq * 8];                   \
    *(float4*)&mv[4] = *(const float4*)&smCM[(N0) + fq * 8 + 4];               \
    *(float4*)&cv[0] = *(const float4*)&smCS[(N0) + fq * 8];                   \
    *(float4*)&cv[4] = *(const float4*)&smCS[(N0) + fq * 8 + 4];               \
    bf16 tb[8];                                                                \
    _Pragma("unroll") for (int i = 0; i < 8; ++i) {                            \
      float fvi = __uint_as_float((unsigned)(unsigned short)FREG[i] << 16);    \
      float pv = __expf(fvi - mv[i]) * cv[i];                                  \
      rs += pv;                                                                \
      tb[i] = __float2bfloat16(pv);                                            \
    }                                                                          \
    *(bf16x8v*)&sB[BUF][fr * 64 + ((fq ^ (fr & 7)) * 8)] = *(bf16x8v*)tb;      \
  }

#define STAGEV(BUF, N0)                                                        \
  _Pragma("unroll") for (int i = 0; i < 4; ++i) {                              \
    int c = i * 512 + tid;                                                     \
    int row = c >> 3, g = c & 7;                                               \
    gload16(Vz + (long)row * NPT + ((N0) & 2047) + ((g ^ (row & 7)) * 8),      \
            &sA[BUF][c * 8]);                                                  \
  }

#define WAITBAR                                                                \
  asm volatile("s_waitcnt vmcnt(1) lgkmcnt(0)" ::: "memory");                  \
  __builtin_amdgcn_s_barrier();

  // prologue
  LOADF(fvA, 0)
  STAGEV(0, 0)
  __syncthreads();  // scales in LDS visible; V(0) + F(0) drained
  EXPW(0, fvA, 0)
  LOADF(fvB, 64)
  __syncthreads();  // PT(0) visible; F(1) drained

#define VP_BODY(CUR, FN, FN2, STEPI)                                           \
  {                                                                            \
    const int sn = (STEPI);                                                    \
    const int nn0 = sn * 64;                                                   \
    STAGEV(CUR ^ 1, nn0 + 64)                                                  \
    LOADF(FN2, nn0 + 128)                                                      \
    if (sn + 1 < 32) EXPW(CUR ^ 1, FN, nn0 + 64)                               \
    bf16x8v bfr[2][2];                                                         \
    _Pragma("unroll") for (int ni = 0; ni < 2; ++ni)                           \
      _Pragma("unroll") for (int ks = 0; ks < 2; ++ks) {                       \
        int rB = wm * 32 + ni * 16 + (lane & 15);                              \
        int g = ks * 4 + (lane >> 4);                                          \
        bfr[ni][ks] = *(const bf16x8v*)&sB[CUR][rB * 64 + ((g ^ (rB & 7)) * 8)]; \
      }                                                                        \
    _Pragma("unroll") for (int mi = 0; mi < 4; ++mi)                           \
      _Pragma("unroll") for (int ks = 0; ks < 2; ++ks) {                       \
        int rA = we * 64 + mi * 16 + (lane & 15);                              \
        int g = ks * 4 + (lane >> 4);                                          \
        bf16x8v af = *(const bf16x8v*)&sA[CUR][rA * 64 + ((g ^ (rA & 7)) * 8)]; \
        _Pragma("unroll") for (int ni = 0; ni < 2; ++ni)                       \
          acc[mi][ni] = MFMA16(af, bfr[ni][ks], acc[mi][ni]);                  \
      }                                                                        \
    WAITBAR                                                                    \
  }

  for (int it = 0; it < 16; ++it) {
    VP_BODY(0, fvB, fvA, 2 * it)
    VP_BODY(1, fvA, fvB, 2 * it + 1)
  }
#undef VP_BODY
#undef WAITBAR
#undef STAGEV
#undef EXPW
#undef LOADF

  rsLds[fr][fq] = rs;
  __syncthreads();
  if (tid < 64) {
    float R = 0.f;
#pragma unroll
    for (int q = 0; q < 8; ++q) R += rsLds[tid][q];
    Sv[tid] = 1.0f / (1e-9f + R);
  }
  __syncthreads();

  float* Hz = Hn + (long)z * STRD;
  bf16* Hb = Htb + (long)z * STRD;
  const int rb = (lane >> 4) * 4, cb = lane & 15;
#pragma unroll
  for (int mi = 0; mi < 4; ++mi) {
    int e0 = we * 64 + mi * 16 + rb;
#pragma unroll
    for (int ni = 0; ni < 2; ++ni) {
      int c = wm * 32 + ni * 16 + cb;
      float scl = Sv[c];
      long base = (long)(m0 + c) * DEMB + e0;
      float4 h = *(const float4*)(Hz + base);
      float r0 = h.x + acc[mi][ni][0] * scl;
      float r1 = h.y + acc[mi][ni][1] * scl;
      float r2 = h.z + acc[mi][ni][2] * scl;
      float r3 = h.w + acc[mi][ni][3] * scl;
      *(float4*)(Hz + base) = float4{r0, r1, r2, r3};
      bf16 hb[4] = {__float2bfloat16(r0), __float2bfloat16(r1),
                    __float2bfloat16(r2), __float2bfloat16(r3)};
      *(uint2*)(Hb + base) = *(uint2*)hb;
    }
  }
}

// ---- pooled[b*n] = row mean of Hn [16384][256] (one wave per row) ----
__global__ void k_pool(const float* __restrict__ Hn, float* __restrict__ pooled) {
  int row = blockIdx.x * 4 + (threadIdx.x >> 6);
  int lane = threadIdx.x & 63;
  float4 v = *(const float4*)(Hn + (long)row * DEMB + lane * 4);
  float s = v.x + v.y + v.z + v.w;
  s = waveReduceSum(s);
  if (lane == 0) pooled[row] = s * (1.0f / DEMB);
}

// ---- fc1: one block per output row j; w row read ONCE, all 8 batches ----
__global__ __launch_bounds__(256) void k_fc1(const float* __restrict__ pooled,
                                             const float* __restrict__ w, const float* __restrict__ bias,
                                             float* __restrict__ f) {
  int j = blockIdx.x;
  const float* wr = w + (long)j * NPT;
  int n0 = threadIdx.x * 8;
  float wl[8];
  *(float4*)&wl[0] = *(const float4*)(wr + n0);
  *(float4*)&wl[4] = *(const float4*)(wr + n0 + 4);
  float part[8];
#pragma unroll
  for (int b = 0; b < 8; ++b) {
    const float* pp = pooled + (long)b * NPT + n0;
    float4 p0 = *(const float4*)pp, p1 = *(const float4*)(pp + 4);
    part[b] = wl[0] * p0.x + wl[1] * p0.y + wl[2] * p0.z + wl[3] * p0.w +
              wl[4] * p1.x + wl[5] * p1.y + wl[6] * p1.z + wl[7] * p1.w;
  }
#pragma unroll
  for (int b = 0; b < 8; ++b) {
    float s = blockReduceSum(part[b]);
    if (threadIdx.x == 0) {
      s += bias[j];
      f[(long)b * NPT + j] = s > 0.f ? s : 0.f;
    }
  }
}

// ---- fc2 ----
__global__ __launch_bounds__(256) void k_fc2(const float* __restrict__ f,
                                             const float* __restrict__ w, const float* __restrict__ bias,
                                             float* __restrict__ out) {
  int b = blockIdx.x;
  float s = 0.f;
  for (int j = threadIdx.x; j < NPT; j += 256) s += f[(long)b * NPT + j] * w[j];
  s = blockReduceSum(s);
  if (threadIdx.x == 0) out[b] = s + bias[0];
}

extern "C" void kernel_launch(void* const* d_in, const int* in_sizes, int n_in,
                              void* d_out, int out_size, void* d_ws, size_t ws_size,
                              hipStream_t stream) {
  const float* X    = (const float*)d_in[0];
  const float* W1   = (const float*)d_in[1];
  const float* B1   = (const float*)d_in[2];
  const float* G1   = (const float*)d_in[3];
  const float* BE1  = (const float*)d_in[4];
  const float* W2   = (const float*)d_in[5];
  const float* B2   = (const float*)d_in[6];
  const float* G2   = (const float*)d_in[7];
  const float* BE2  = (const float*)d_in[8];
  const float* WQ   = (const float*)d_in[9];
  const float* WK   = (const float*)d_in[10];
  const float* WV   = (const float*)d_in[11];
  const float* FC1W = (const float*)d_in[12];
  const float* FC1B = (const float*)d_in[13];
  const float* FC2W = (const float*)d_in[14];
  const float* FC2B = (const float*)d_in[15];
  float* OUT = (float*)d_out;

  // ---- workspace carve-out ----
  char* p = (char*)d_ws;
  auto alloc = [&](size_t bytes) -> char* {
    char* r = p;
    p += (bytes + 255) & ~(size_t)255;
    return r;
  };
  float* H1t  = (float*)alloc((size_t)BATCH * NPT * DMID * 4);
  bf16*  H1tb = (bf16*)alloc((size_t)BATCH * NPT * DMID * 2);
  float* Hn   = (float*)alloc((size_t)BATCH * STRD * 4);   // [b*n][256] f32
  bf16*  Htb  = (bf16*)alloc((size_t)BATCH * STRD * 2);    // [b*n][256] bf16
  bf16*  QKt  = (bf16*)alloc((size_t)BATCH * QKS * 2);     // [b][n][512]
  bf16*  Vb   = (bf16*)alloc((size_t)BATCH * STRD * 2);    // [b][e][n]
  bf16*  W2b  = (bf16*)alloc((size_t)DEMB * DMID * 2);
  bf16*  WQKb = (bf16*)alloc((size_t)NSA * 512 * DEMB * 2);
  bf16*  WVb  = (bf16*)alloc((size_t)NSA * DEMB * DEMB * 2);
  float* pS   = (float*)alloc(128 * 64 * 4);
  float* pS2  = (float*)alloc(128 * 64 * 4);
  float* pA2  = (float*)alloc(128 * DEMB * 4);
  float* pB2  = (float*)alloc(128 * DEMB * 4);
  float* sa1  = (float*)alloc(64 * 4);
  float* sb1  = (float*)alloc(64 * 4);
  float* sa2  = (float*)alloc(256 * 4);
  float* sb2  = (float*)alloc(256 * 4);
  float* CM   = (float*)alloc((size_t)BATCH * NPT * 4);
  float* CSi  = (float*)alloc((size_t)BATCH * NPT * 4);
  float* PM   = (float*)alloc((size_t)BATCH * 16 * NPT * 4);
  float* PSm  = (float*)alloc((size_t)BATCH * 16 * NPT * 4);
  float* POOL = (float*)alloc((size_t)BATCH * NPT * 4);
  float* FH   = (float*)alloc((size_t)BATCH * NPT * 4);
  size_t used = (size_t)(p - (char*)d_ws);
  const size_t per_g = (size_t)NN * 2;  // F bf16 (8MB per batch)
  int G = 8;
  while (G > 1 && used + (size_t)G * per_g + 1024 > ws_size) G >>= 1;
  bf16* F = (bf16*)alloc((size_t)G * NN * 2);

  // ---- weight converts ----
  k_cvt<<<(DEMB * DMID + 255) / 256, 256, 0, stream>>>(W2, W2b, DEMB * DMID);
  int nqk = NSA * 512 * DEMB;
  k_cvtqk<<<nqk / 256, 256, 0, stream>>>(WQ, WK, WQKb);
  int nw = NSA * DEMB * DEMB;
  k_cvt<<<(nw + 255) / 256, 256, 0, stream>>>(WV, WVb, nw);

  // ---- conv1 + BN1 + ReLU (-> H1tb bf16 [b*n][64]) ----
  long szh1 = (long)BATCH * NPT * DMID;
  k_conv1t<<<(int)(szh1 / 256), 256, 0, stream>>>(X, W1, B1, H1t);
  k_bn1a<<<128, 256, 0, stream>>>(H1t, pS, pS2);
  k_bn1b<<<1, 64, 0, stream>>>(pS, pS2, G1, BE1, sa1, sb1);
  k_bn1apply<<<(int)(szh1 / 256), 256, 0, stream>>>(H1t, sa1, sb1, H1tb);

  // ---- conv2 (MFMA, [n][e] layout) + BN2 + ReLU -> Hn f32 + Htb bf16 ----
  k_mgemm<2><<<dim3(2, 128, 1), 256, 0, stream>>>(H1tb, 0, DMID, W2b, 0, DMID,
                                                  Hn, 0, DEMB, DMID, B2, nullptr, nullptr, 0, 0);
  k_bn2a<<<128, 256, 0, stream>>>(Hn, pA2, pB2);
  k_bn2b<<<1, 256, 0, stream>>>(pA2, pB2, G2, BE2, sa2, sb2);
  k_bnapply2<<<(int)(BATCH * STRD / 256), 256, 0, stream>>>(Hn, Htb, sa2, sb2);

  // ---- SA layers (batch b pinned to XCD b across the whole chain) ----
  for (int l = 0; l < NSA; ++l) {
    // QKt[n][0..511] = Htb . [Wq;Wk]^T : grid 8*64 pinned, bx = t%4, by = t/4
    k_mgemm<1><<<dim3(8 * 64), 256, 0, stream>>>(Htb, STRD, DEMB, WQKb + (long)l * 512 * DEMB, 0, DEMB,
                                                 QKt, QKS, 512, DEMB, nullptr, nullptr, nullptr, 8, 4);
    // V[e][n] : A=Wv (M=256), B=Htb (N=2048) : grid 8*32 pinned, bx = t%16, by = t/16
    k_mgemm<1><<<dim3(8 * 32), 256, 0, stream>>>(WVb + (long)l * DEMB * DEMB, 0, DEMB, Htb, STRD, DEMB,
                                                 Vb, STRD, NPT, DEMB, nullptr, nullptr, nullptr, 8, 16);
    for (int b0 = 0; b0 < BATCH; b0 += G) {
      // F[m][n] = sum_a Kt[m][a] Qt[n][a] (= E^T), bf16 + fused exact column stats
      k_mgemm<0><<<dim3(256 * G), 256, 0, stream>>>(QKt + 256 + b0 * QKS, QKS, 512,
                                                    QKt + b0 * QKS, QKS, 512,
                                                    F, NN, NPT, DEMB, nullptr, PM, PSm, G, 16);
      k_cms_fin<<<G * NPT / 256, 256, 0, stream>>>(PM, PSm, CM, CSi);
      // Hn[m][e] += S[m] * sum_n V[e][n] PT[m][n]; Htb = bf16(Hn)
      k_vp<<<dim3(32 * G), 512, 0, stream>>>(F, CM, CSi, Vb + b0 * STRD,
                                             Hn + b0 * STRD, Htb + b0 * STRD, G);
    }
  }

  // ---- head ----
  k_pool<<<(BATCH * NPT) / 4, 256, 0, stream>>>(Hn, POOL);
  k_fc1<<<NPT, 256, 0, stream>>>(POOL, FC1W, FC1B, FH);
  k_fc2<<<BATCH, 256, 0, stream>>>(FH, FC2W, FC2B, OUT);
}

// Round 18
// 434.746 us; speedup vs baseline: 1.0035x; 1.0014x over previous
//
#include <hip/hip_runtime.h>
#include <hip/hip_bf16.h>

typedef __hip_bfloat16 bf16;
#define DEVI __device__ __forceinline__

// Problem constants
static constexpr int BATCH = 8;
static constexpr int NPT   = 2048;
static constexpr int DMID  = 64;
static constexpr int DEMB  = 256;
static constexpr int NSA   = 4;
static constexpr long STRD = (long)DEMB * NPT;  // 524288
static constexpr long QKS  = (long)NPT * 512;   // per-batch stride of QKt
static constexpr long NN   = (long)NPT * NPT;   // 4194304

typedef __attribute__((ext_vector_type(4))) float f32x4;
typedef __attribute__((ext_vector_type(8))) short bf16x8v;

DEVI f32x4 MFMA16(bf16x8v a, bf16x8v b, f32x4 c) {
  return __builtin_amdgcn_mfma_f32_16x16x32_bf16(a, b, c, 0, 0, 0);
}

DEVI void gload16(const bf16* g, bf16* l) {
  __builtin_amdgcn_global_load_lds(
      (const __attribute__((address_space(1))) void*)g,
      (__attribute__((address_space(3))) void*)l, 16, 0, 0);
}

DEVI float waveReduceSum(float v) {
#pragma unroll
  for (int o = 32; o > 0; o >>= 1) v += __shfl_down(v, o, 64);
  return v;
}
DEVI float blockReduceSum(float v) {
  __shared__ float sm[4];
  int lane = threadIdx.x & 63, wid = threadIdx.x >> 6;
  __syncthreads();
  v = waveReduceSum(v);
  if (lane == 0) sm[wid] = v;
  __syncthreads();
  return sm[0] + sm[1] + sm[2] + sm[3];
}

// ---- fp32 -> bf16 convert ----
__global__ void k_cvt(const float* __restrict__ in, bf16* __restrict__ out, int n) {
  int i = blockIdx.x * 256 + threadIdx.x;
  if (i < n) out[i] = __float2bfloat16(in[i]);
}

// ---- concat-convert Wq,Wk -> WQKb [l][512][256] bf16 ----
__global__ void k_cvtqk(const float* __restrict__ wq, const float* __restrict__ wk,
                        bf16* __restrict__ o) {
  int idx = blockIdx.x * 256 + threadIdx.x;  // NSA*512*256
  int c = idx & 255;
  int r = (idx >> 8) & 511;
  int l = idx >> 17;
  float v = (r < 256) ? wq[((l << 8) + r) * 256 + c] : wk[((l << 8) + (r - 256)) * 256 + c];
  o[idx] = __float2bfloat16(v);
}

// ---- conv1: H1t[b][n][o] = sum_c x[b,n,c]*w1[o,c] + b1[o] ----
__global__ void k_conv1t(const float* __restrict__ x, const float* __restrict__ w1,
                         const float* __restrict__ b1, float* __restrict__ h1t) {
  long idx = (long)blockIdx.x * 256 + threadIdx.x;  // [b*n][o]
  int o = idx & 63;
  long bn = idx >> 6;
  const float* xp = x + bn * 3;
  h1t[idx] = b1[o] + xp[0] * w1[o * 3] + xp[1] * w1[o * 3 + 1] + xp[2] * w1[o * 3 + 2];
}

// ---- BN1 stats on H1t [16384][64] ----
__global__ __launch_bounds__(256) void k_bn1a(const float* __restrict__ h, float* __restrict__ pS,
                                              float* __restrict__ pS2) {
  int c = threadIdx.x & 63, rg = threadIdx.x >> 6;
  long r0 = (long)blockIdx.x * 128 + rg * 32;
  float s = 0.f, s2 = 0.f;
  for (int i = 0; i < 32; ++i) {
    float v = h[(r0 + i) * 64 + c];
    s += v; s2 += v * v;
  }
  __shared__ float smS[256], smS2[256];
  smS[threadIdx.x] = s; smS2[threadIdx.x] = s2;
  __syncthreads();
  if (threadIdx.x < 64) {
    float a = 0.f, b = 0.f;
#pragma unroll
    for (int g = 0; g < 4; ++g) { a += smS[g * 64 + c]; b += smS2[g * 64 + c]; }
    pS[blockIdx.x * 64 + c] = a;
    pS2[blockIdx.x * 64 + c] = b;
  }
}
__global__ void k_bn1b(const float* __restrict__ pS, const float* __restrict__ pS2,
                       const float* __restrict__ g, const float* __restrict__ be,
                       float* __restrict__ sa, float* __restrict__ sb) {
  int c = threadIdx.x;
  if (c >= 64) return;
  float s = 0.f, s2 = 0.f;
  for (int i = 0; i < 128; ++i) { s += pS[i * 64 + c]; s2 += pS2[i * 64 + c]; }
  const float inv = 1.0f / (BATCH * NPT);
  float m = s * inv, var = s2 * inv - m * m;
  float A = rsqrtf(var + 1e-5f) * g[c];
  sa[c] = A; sb[c] = be[c] - m * A;
}
__global__ void k_bn1apply(const float* __restrict__ h, const float* __restrict__ sa,
                           const float* __restrict__ sb, bf16* __restrict__ o) {
  long idx = (long)blockIdx.x * 256 + threadIdx.x;
  int c = idx & 63;
  float v = fmaf(h[idx], sa[c], sb[c]);
  o[idx] = __float2bfloat16(v > 0.f ? v : 0.f);
}

// ---- BN2 stats on Hn [16384][256] (per-column = per-channel) ----
__global__ __launch_bounds__(256) void k_bn2a(const float* __restrict__ h,
                                              float* __restrict__ pA, float* __restrict__ pB) {
  int c = threadIdx.x;
  long r0 = (long)blockIdx.x * 128;
  float s = 0.f, s2 = 0.f;
  for (int i = 0; i < 128; ++i) {
    float v = h[(r0 + i) * DEMB + c];
    s += v; s2 += v * v;
  }
  pA[blockIdx.x * DEMB + c] = s;
  pB[blockIdx.x * DEMB + c] = s2;
}
__global__ void k_bn2b(const float* __restrict__ pA, const float* __restrict__ pB,
                       const float* __restrict__ g, const float* __restrict__ be,
                       float* __restrict__ sa, float* __restrict__ sb) {
  int c = threadIdx.x;  // 256 threads
  float s = 0.f, s2 = 0.f;
  for (int i = 0; i < 128; ++i) { s += pA[i * DEMB + c]; s2 += pB[i * DEMB + c]; }
  const float inv = 1.0f / (BATCH * NPT);
  float m = s * inv, var = s2 * inv - m * m;
  float A = rsqrtf(var + 1e-5f) * g[c];
  sa[c] = A; sb[c] = be[c] - m * A;
}
// BN2 apply + ReLU: write Hn (f32 residual) and Htb (bf16 operand)
__global__ void k_bnapply2(float* __restrict__ hn, bf16* __restrict__ htb,
                           const float* __restrict__ sa, const float* __restrict__ sb) {
  long idx = (long)blockIdx.x * 256 + threadIdx.x;
  int c = idx & (DEMB - 1);
  float v = fmaf(hn[idx], sa[c], sb[c]);
  v = v > 0.f ? v : 0.f;
  hn[idx] = v;
  htb[idx] = __float2bfloat16(v);
}

// ---- MFMA GEMM, B^T form: C[M][N] = A[M][K] . B[N][K]^T ; 128x128 tile, BK=64 ----
// XOR-swizzled LDS (granule ^= row&7) on both staging-source and read.
// nz > 0: 1-D grid, bz = bid % nz (XCD-pin), bx = t % gx, by = t / gx.
// MODE 0: C bf16 = acc + fused column-softmax partials (PM/PS)
// MODE 1: C bf16 = acc
// MODE 2: C f32 = acc + bias[col]
template <int MODE>
__global__ __launch_bounds__(256) void k_mgemm(
    const bf16* __restrict__ A, long aStr, int ldA,
    const bf16* __restrict__ B, long bStr, int ldB,
    void* __restrict__ Cv, long cStr, int ldC,
    int K,
    const float* __restrict__ bias,
    float* __restrict__ PMo, float* __restrict__ PSo, int nz, int gx) {
  __shared__ __align__(16) bf16 sA[128 * 64];
  __shared__ __align__(16) bf16 sB[128 * 64];
  __shared__ float smx[4][64], ssx[4][64];
  int bx, by, bz;
  if (nz > 0) {
    bz = blockIdx.x % nz;
    int t = blockIdx.x / nz;
    bx = t % gx;
    by = t / gx;
  } else {
    bx = blockIdx.x; by = blockIdx.y; bz = blockIdx.z;
  }
  A += aStr * bz;
  B += bStr * bz;
  const int bm = by * 128, bn = bx * 128;
  const int tid = threadIdx.x;
  const int lane = tid & 63, wv = tid >> 6;
  const int wr = (wv >> 1) * 64, wc = (wv & 1) * 64;
  f32x4 acc[4][4] = {};

  for (int k0 = 0; k0 < K; k0 += 64) {
#pragma unroll
    for (int i = 0; i < 4; ++i) {
      int c = i * 256 + tid;
      int row = c >> 3, g = c & 7;
      int gs = (g ^ (row & 7)) * 8;
      gload16(A + (long)(bm + row) * ldA + k0 + gs, sA + c * 8);
      gload16(B + (long)(bn + row) * ldB + k0 + gs, sB + c * 8);
    }
    __syncthreads();
    bf16x8v af[4][2], bfr[4][2];
#pragma unroll
    for (int mi = 0; mi < 4; ++mi)
#pragma unroll
      for (int ks = 0; ks < 2; ++ks) {
        int rA = wr + mi * 16 + (lane & 15);
        int rB = wc + mi * 16 + (lane & 15);
        int g = ks * 4 + (lane >> 4);
        af[mi][ks]  = *(const bf16x8v*)&sA[rA * 64 + ((g ^ (rA & 7)) * 8)];
        bfr[mi][ks] = *(const bf16x8v*)&sB[rB * 64 + ((g ^ (rB & 7)) * 8)];
      }
#pragma unroll
    for (int ks = 0; ks < 2; ++ks)
#pragma unroll
      for (int mi = 0; mi < 4; ++mi)
#pragma unroll
        for (int ni = 0; ni < 4; ++ni)
          acc[mi][ni] = MFMA16(af[mi][ks], bfr[ni][ks], acc[mi][ni]);
    __syncthreads();
  }

  const int rb = (lane >> 4) * 4, cb = lane & 15;
  if constexpr (MODE == 0 || MODE == 1) {
    bf16* C = (bf16*)Cv + cStr * bz;
#pragma unroll
    for (int mi = 0; mi < 4; ++mi)
#pragma unroll
      for (int ni = 0; ni < 4; ++ni) {
        int r0 = bm + wr + mi * 16 + rb, c0 = bn + wc + ni * 16 + cb;
#pragma unroll
        for (int k = 0; k < 4; ++k)
          C[(long)(r0 + k) * ldC + c0] = __float2bfloat16(acc[mi][ni][k]);
      }
  } else {
    float* C = (float*)Cv + cStr * bz;
#pragma unroll
    for (int mi = 0; mi < 4; ++mi)
#pragma unroll
      for (int ni = 0; ni < 4; ++ni) {
        int r0 = bm + wr + mi * 16 + rb, c0 = bn + wc + ni * 16 + cb;
        float badd = bias[c0];
#pragma unroll
        for (int k = 0; k < 4; ++k) {
          int r = r0 + k;
          C[(long)r * ldC + c0] = acc[mi][ni][k] + badd;
        }
      }
  }

  if constexpr (MODE == 0) {
    // per-column (over this block's 128 rows) online-softmax partials (exact fp32)
    float cm[4], cs[4];
#pragma unroll
    for (int ni = 0; ni < 4; ++ni) {
      float m = -3.0e38f;
#pragma unroll
      for (int mi = 0; mi < 4; ++mi)
#pragma unroll
        for (int k = 0; k < 4; ++k) m = fmaxf(m, acc[mi][ni][k]);
      float s = 0.f;
#pragma unroll
      for (int mi = 0; mi < 4; ++mi)
#pragma unroll
        for (int k = 0; k < 4; ++k) s += __expf(acc[mi][ni][k] - m);
#pragma unroll
      for (int off = 16; off <= 32; off <<= 1) {
        float mo = __shfl_xor(m, off, 64);
        float so = __shfl_xor(s, off, 64);
        float M = fmaxf(m, mo);
        s = s * __expf(m - M) + so * __expf(mo - M);
        m = M;
      }
      cm[ni] = m; cs[ni] = s;
    }
    __syncthreads();  // LDS reads of K-loop complete; reuse smx/ssx safely
    if (lane < 16) {
#pragma unroll
      for (int ni = 0; ni < 4; ++ni) {
        smx[wv][ni * 16 + lane] = cm[ni];
        ssx[wv][ni * 16 + lane] = cs[ni];
      }
    }
    __syncthreads();
    if (tid < 128) {
      int half = tid >> 6, c64 = tid & 63;
      float m1 = smx[half][c64], s1 = ssx[half][c64];
      float m2 = smx[half + 2][c64], s2 = ssx[half + 2][c64];
      float M = fmaxf(m1, m2);
      float S = s1 * __expf(m1 - M) + s2 * __expf(m2 - M);
      long o = ((long)bz * 16 + by) * NPT + bn + half * 64 + c64;
      PMo[o] = M;
      PSo[o] = S;
    }
  }
}

// ---- fused colstat-combine + normalize + rowsum + V.P GEMM ----
// Prologue combines the 16 PM/PS partials per column directly into LDS
// (exactly the same per-column arithmetic the old k_cms_fin used).
// Tile 256e x 64m; 512 threads = 8 waves (4e x 2m); grid 32*nz;
// z = bid % nz pins each batch's V to one XCD's L2.
// Epilogue: Hn[m][e] += acc*scl (f32) and (if wHtb) Htb[m][e] = bf16(new).
// Per-step sync: counted s_waitcnt vmcnt(1)+lgkmcnt(0)+s_barrier; issue order
// STAGEV(4) then LOADF(1) keeps the F prefetch in flight across the barrier.
__global__ __launch_bounds__(512) void k_vp(const bf16* __restrict__ F,
                                            const float* __restrict__ PM,
                                            const float* __restrict__ PSm,
                                            const bf16* __restrict__ V,
                                            float* __restrict__ Hn,
                                            bf16* __restrict__ Htb, int nz, int wHtb) {
  __shared__ __align__(16) bf16 sA[2][256 * 64];  // V tiles (double-buffered)
  __shared__ __align__(16) bf16 sB[2][64 * 64];   // PT tiles (double-buffered)
  __shared__ float rsLds[64][8];
  __shared__ float Sv[64];
  __shared__ float smCM[NPT], smCS[NPT];
  const int z = blockIdx.x % nz;
  const int m0 = (blockIdx.x / nz) * 64;
  const int tid = threadIdx.x;
  const int lane = tid & 63, wv = tid >> 6;
  const int we = wv & 3;   // e-quarter 0..3 (64 rows)
  const int wm = wv >> 2;  // m-half 0..1 (32 cols)
  const int fr = tid >> 3; // F row 0..63
  const int fq = tid & 7;  // F col chunk 0..7
  const bf16* Vz = V + (long)z * STRD;
  const bf16* Frp = F + (long)z * NN + (long)(m0 + fr) * NPT + fq * 8;
  f32x4 acc[4][2] = {};
  float rs = 0.f;
  bf16x8v fvA, fvB;

  // one-time: combine 16 column-softmax partials for this batch into LDS
  {
    const float* pm = PM + (long)z * 16 * NPT;
    const float* ps = PSm + (long)z * 16 * NPT;
#pragma unroll
    for (int i = 0; i < 4; ++i) {
      int n = i * 512 + tid;
      float m = -3.0e38f;
#pragma unroll
      for (int y = 0; y < 16; ++y) m = fmaxf(m, pm[(long)y * NPT + n]);
      float s = 0.f;
#pragma unroll
      for (int y = 0; y < 16; ++y) s += ps[(long)y * NPT + n] * __expf(pm[(long)y * NPT + n] - m);
      smCM[n] = m;
      smCS[n] = 1.0f / s;
    }
  }

#define LOADF(FREG, N0) FREG = *(const bf16x8v*)(Frp + ((N0) & 2047));

#define EXPW(BUF, FREG, N0)                                                    \
  {                                                                            \
    float mv[8], cv[8];                                                        \
    *(float4*)&mv[0] = *(const float4*)&smCM[(N0) + fq * 8];                   \
    *(float4*)&mv[4] = *(const float4*)&smCM[(N0) + fq * 8 + 4];               \
    *(float4*)&cv[0] = *(const float4*)&smCS[(N0) + fq * 8];                   \
    *(float4*)&cv[4] = *(const float4*)&smCS[(N0) + fq * 8 + 4];               \
    bf16 tb[8];                                                                \
    _Pragma("unroll") for (int i = 0; i < 8; ++i) {                            \
      float fvi = __uint_as_float((unsigned)(unsigned short)FREG[i] << 16);    \
      float pv = __expf(fvi - mv[i]) * cv[i];                                  \
      rs += pv;                                                                \
      tb[i] = __float2bfloat16(pv);                                            \
    }                                                                          \
    *(bf16x8v*)&sB[BUF][fr * 64 + ((fq ^ (fr & 7)) * 8)] = *(bf16x8v*)tb;      \
  }

#define STAGEV(BUF, N0)                                                        \
  _Pragma("unroll") for (int i = 0; i < 4; ++i) {                              \
    int c = i * 512 + tid;                                                     \
    int row = c >> 3, g = c & 7;                                               \
    gload16(Vz + (long)row * NPT + ((N0) & 2047) + ((g ^ (row & 7)) * 8),      \
            &sA[BUF][c * 8]);                                                  \
  }

#define WAITBAR                                                                \
  asm volatile("s_waitcnt vmcnt(1) lgkmcnt(0)" ::: "memory");                  \
  __builtin_amdgcn_s_barrier();

  // prologue
  LOADF(fvA, 0)
  STAGEV(0, 0)
  __syncthreads();  // scales in LDS visible; V(0) + F(0) drained
  EXPW(0, fvA, 0)
  LOADF(fvB, 64)
  __syncthreads();  // PT(0) visible; F(1) drained

#define VP_BODY(CUR, FN, FN2, STEPI)                                           \
  {                                                                            \
    const int sn = (STEPI);                                                    \
    const int nn0 = sn * 64;                                                   \
    STAGEV(CUR ^ 1, nn0 + 64)                                                  \
    LOADF(FN2, nn0 + 128)                                                      \
    if (sn + 1 < 32) EXPW(CUR ^ 1, FN, nn0 + 64)                               \
    bf16x8v bfr[2][2];                                                         \
    _Pragma("unroll") for (int ni = 0; ni < 2; ++ni)                           \
      _Pragma("unroll") for (int ks = 0; ks < 2; ++ks) {                       \
        int rB = wm * 32 + ni * 16 + (lane & 15);                              \
        int g = ks * 4 + (lane >> 4);                                          \
        bfr[ni][ks] = *(const bf16x8v*)&sB[CUR][rB * 64 + ((g ^ (rB & 7)) * 8)]; \
      }                                                                        \
    _Pragma("unroll") for (int mi = 0; mi < 4; ++mi)                           \
      _Pragma("unroll") for (int ks = 0; ks < 2; ++ks) {                       \
        int rA = we * 64 + mi * 16 + (lane & 15);                              \
        int g = ks * 4 + (lane >> 4);                                          \
        bf16x8v af = *(const bf16x8v*)&sA[CUR][rA * 64 + ((g ^ (rA & 7)) * 8)]; \
        _Pragma("unroll") for (int ni = 0; ni < 2; ++ni)                       \
          acc[mi][ni] = MFMA16(af, bfr[ni][ks], acc[mi][ni]);                  \
      }                                                                        \
    WAITBAR                                                                    \
  }

  for (int it = 0; it < 16; ++it) {
    VP_BODY(0, fvB, fvA, 2 * it)
    VP_BODY(1, fvA, fvB, 2 * it + 1)
  }
#undef VP_BODY
#undef WAITBAR
#undef STAGEV
#undef EXPW
#undef LOADF

  rsLds[fr][fq] = rs;
  __syncthreads();
  if (tid < 64) {
    float R = 0.f;
#pragma unroll
    for (int q = 0; q < 8; ++q) R += rsLds[tid][q];
    Sv[tid] = 1.0f / (1e-9f + R);
  }
  __syncthreads();

  float* Hz = Hn + (long)z * STRD;
  bf16* Hb = Htb + (long)z * STRD;
  const int rb = (lane >> 4) * 4, cb = lane & 15;
#pragma unroll
  for (int mi = 0; mi < 4; ++mi) {
    int e0 = we * 64 + mi * 16 + rb;
#pragma unroll
    for (int ni = 0; ni < 2; ++ni) {
      int c = wm * 32 + ni * 16 + cb;
      float scl = Sv[c];
      long base = (long)(m0 + c) * DEMB + e0;
      float4 h = *(const float4*)(Hz + base);
      float r0 = h.x + acc[mi][ni][0] * scl;
      float r1 = h.y + acc[mi][ni][1] * scl;
      float r2 = h.z + acc[mi][ni][2] * scl;
      float r3 = h.w + acc[mi][ni][3] * scl;
      *(float4*)(Hz + base) = float4{r0, r1, r2, r3};
      if (wHtb) {
        bf16 hb[4] = {__float2bfloat16(r0), __float2bfloat16(r1),
                      __float2bfloat16(r2), __float2bfloat16(r3)};
        *(uint2*)(Hb + base) = *(uint2*)hb;
      }
    }
  }
}

// ---- pooled[b*n] = row mean of Hn [16384][256] (one wave per row) ----
__global__ void k_pool(const float* __restrict__ Hn, float* __restrict__ pooled) {
  int row = blockIdx.x * 4 + (threadIdx.x >> 6);
  int lane = threadIdx.x & 63;
  float4 v = *(const float4*)(Hn + (long)row * DEMB + lane * 4);
  float s = v.x + v.y + v.z + v.w;
  s = waveReduceSum(s);
  if (lane == 0) pooled[row] = s * (1.0f / DEMB);
}

// ---- fc1: one block per output row j; w row read ONCE, all 8 batches ----
__global__ __launch_bounds__(256) void k_fc1(const float* __restrict__ pooled,
                                             const float* __restrict__ w, const float* __restrict__ bias,
                                             float* __restrict__ f) {
  int j = blockIdx.x;
  const float* wr = w + (long)j * NPT;
  int n0 = threadIdx.x * 8;
  float wl[8];
  *(float4*)&wl[0] = *(const float4*)(wr + n0);
  *(float4*)&wl[4] = *(const float4*)(wr + n0 + 4);
  float part[8];
#pragma unroll
  for (int b = 0; b < 8; ++b) {
    const float* pp = pooled + (long)b * NPT + n0;
    float4 p0 = *(const float4*)pp, p1 = *(const float4*)(pp + 4);
    part[b] = wl[0] * p0.x + wl[1] * p0.y + wl[2] * p0.z + wl[3] * p0.w +
              wl[4] * p1.x + wl[5] * p1.y + wl[6] * p1.z + wl[7] * p1.w;
  }
#pragma unroll
  for (int b = 0; b < 8; ++b) {
    float s = blockReduceSum(part[b]);
    if (threadIdx.x == 0) {
      s += bias[j];
      f[(long)b * NPT + j] = s > 0.f ? s : 0.f;
    }
  }
}

// ---- fc2 ----
__global__ __launch_bounds__(256) void k_fc2(const float* __restrict__ f,
                                             const float* __restrict__ w, const float* __restrict__ bias,
                                             float* __restrict__ out) {
  int b = blockIdx.x;
  float s = 0.f;
  for (int j = threadIdx.x; j < NPT; j += 256) s += f[(long)b * NPT + j] * w[j];
  s = blockReduceSum(s);
  if (threadIdx.x == 0) out[b] = s + bias[0];
}

extern "C" void kernel_launch(void* const* d_in, const int* in_sizes, int n_in,
                              void* d_out, int out_size, void* d_ws, size_t ws_size,
                              hipStream_t stream) {
  const float* X    = (const float*)d_in[0];
  const float* W1   = (const float*)d_in[1];
  const float* B1   = (const float*)d_in[2];
  const float* G1   = (const float*)d_in[3];
  const float* BE1  = (const float*)d_in[4];
  const float* W2   = (const float*)d_in[5];
  const float* B2   = (const float*)d_in[6];
  const float* G2   = (const float*)d_in[7];
  const float* BE2  = (const float*)d_in[8];
  const float* WQ   = (const float*)d_in[9];
  const float* WK   = (const float*)d_in[10];
  const float* WV   = (const float*)d_in[11];
  const float* FC1W = (const float*)d_in[12];
  const float* FC1B = (const float*)d_in[13];
  const float* FC2W = (const float*)d_in[14];
  const float* FC2B = (const float*)d_in[15];
  float* OUT = (float*)d_out;

  // ---- workspace carve-out ----
  char* p = (char*)d_ws;
  auto alloc = [&](size_t bytes) -> char* {
    char* r = p;
    p += (bytes + 255) & ~(size_t)255;
    return r;
  };
  float* H1t  = (float*)alloc((size_t)BATCH * NPT * DMID * 4);
  bf16*  H1tb = (bf16*)alloc((size_t)BATCH * NPT * DMID * 2);
  float* Hn   = (float*)alloc((size_t)BATCH * STRD * 4);   // [b*n][256] f32
  bf16*  Htb  = (bf16*)alloc((size_t)BATCH * STRD * 2);    // [b*n][256] bf16
  bf16*  QKt  = (bf16*)alloc((size_t)BATCH * QKS * 2);     // [b][n][512]
  bf16*  Vb   = (bf16*)alloc((size_t)BATCH * STRD * 2);    // [b][e][n]
  bf16*  W2b  = (bf16*)alloc((size_t)DEMB * DMID * 2);
  bf16*  WQKb = (bf16*)alloc((size_t)NSA * 512 * DEMB * 2);
  bf16*  WVb  = (bf16*)alloc((size_t)NSA * DEMB * DEMB * 2);
  float* pS   = (float*)alloc(128 * 64 * 4);
  float* pS2  = (float*)alloc(128 * 64 * 4);
  float* pA2  = (float*)alloc(128 * DEMB * 4);
  float* pB2  = (float*)alloc(128 * DEMB * 4);
  float* sa1  = (float*)alloc(64 * 4);
  float* sb1  = (float*)alloc(64 * 4);
  float* sa2  = (float*)alloc(256 * 4);
  float* sb2  = (float*)alloc(256 * 4);
  float* PM   = (float*)alloc((size_t)BATCH * 16 * NPT * 4);
  float* PSm  = (float*)alloc((size_t)BATCH * 16 * NPT * 4);
  float* POOL = (float*)alloc((size_t)BATCH * NPT * 4);
  float* FH   = (float*)alloc((size_t)BATCH * NPT * 4);
  size_t used = (size_t)(p - (char*)d_ws);
  const size_t per_g = (size_t)NN * 2;  // F bf16 (8MB per batch)
  int G = 8;
  while (G > 1 && used + (size_t)G * per_g + 1024 > ws_size) G >>= 1;
  bf16* F = (bf16*)alloc((size_t)G * NN * 2);

  // ---- weight converts ----
  k_cvt<<<(DEMB * DMID + 255) / 256, 256, 0, stream>>>(W2, W2b, DEMB * DMID);
  int nqk = NSA * 512 * DEMB;
  k_cvtqk<<<nqk / 256, 256, 0, stream>>>(WQ, WK, WQKb);
  int nw = NSA * DEMB * DEMB;
  k_cvt<<<(nw + 255) / 256, 256, 0, stream>>>(WV, WVb, nw);

  // ---- conv1 + BN1 + ReLU (-> H1tb bf16 [b*n][64]) ----
  long szh1 = (long)BATCH * NPT * DMID;
  k_conv1t<<<(int)(szh1 / 256), 256, 0, stream>>>(X, W1, B1, H1t);
  k_bn1a<<<128, 256, 0, stream>>>(H1t, pS, pS2);
  k_bn1b<<<1, 64, 0, stream>>>(pS, pS2, G1, BE1, sa1, sb1);
  k_bn1apply<<<(int)(szh1 / 256), 256, 0, stream>>>(H1t, sa1, sb1, H1tb);

  // ---- conv2 (MFMA, [n][e] layout) + BN2 + ReLU -> Hn f32 + Htb bf16 ----
  k_mgemm<2><<<dim3(2, 128, 1), 256, 0, stream>>>(H1tb, 0, DMID, W2b, 0, DMID,
                                                  Hn, 0, DEMB, DMID, B2, nullptr, nullptr, 0, 0);
  k_bn2a<<<128, 256, 0, stream>>>(Hn, pA2, pB2);
  k_bn2b<<<1, 256, 0, stream>>>(pA2, pB2, G2, BE2, sa2, sb2);
  k_bnapply2<<<(int)(BATCH * STRD / 256), 256, 0, stream>>>(Hn, Htb, sa2, sb2);

  // ---- SA layers (batch b pinned to XCD b across the whole chain) ----
  for (int l = 0; l < NSA; ++l) {
    // QKt[n][0..511] = Htb . [Wq;Wk]^T : grid 8*64 pinned, bx = t%4, by = t/4
    k_mgemm<1><<<dim3(8 * 64), 256, 0, stream>>>(Htb, STRD, DEMB, WQKb + (long)l * 512 * DEMB, 0, DEMB,
                                                 QKt, QKS, 512, DEMB, nullptr, nullptr, nullptr, 8, 4);
    // V[e][n] : A=Wv (M=256), B=Htb (N=2048) : grid 8*32 pinned, bx = t%16, by = t/16
    k_mgemm<1><<<dim3(8 * 32), 256, 0, stream>>>(WVb + (long)l * DEMB * DEMB, 0, DEMB, Htb, STRD, DEMB,
                                                 Vb, STRD, NPT, DEMB, nullptr, nullptr, nullptr, 8, 16);
    for (int b0 = 0; b0 < BATCH; b0 += G) {
      // F[m][n] = sum_a Kt[m][a] Qt[n][a] (= E^T), bf16 + fused exact column stats
      k_mgemm<0><<<dim3(256 * G), 256, 0, stream>>>(QKt + 256 + b0 * QKS, QKS, 512,
                                                    QKt + b0 * QKS, QKS, 512,
                                                    F, NN, NPT, DEMB, nullptr, PM, PSm, G, 16);
      // Hn[m][e] += S[m] * sum_n V[e][n] PT[m][n]; Htb = bf16(Hn) (not last layer)
      k_vp<<<dim3(32 * G), 512, 0, stream>>>(F, PM, PSm, Vb + b0 * STRD,
                                             Hn + b0 * STRD, Htb + b0 * STRD, G,
                                             (l < NSA - 1) ? 1 : 0);
    }
  }

  // ---- head ----
  k_pool<<<(BATCH * NPT) / 4, 256, 0, stream>>>(Hn, POOL);
  k_fc1<<<NPT, 256, 0, stream>>>(POOL, FC1W, FC1B, FH);
  k_fc2<<<BATCH, 256, 0, stream>>>(FH, FC2W, FC2B, OUT);
}

// Round 19
// 401.075 us; speedup vs baseline: 1.0877x; 1.0840x over previous
//
#include <hip/hip_runtime.h>
#include <hip/hip_bf16.h>

typedef __hip_bfloat16 bf16;
#define DEVI __device__ __forceinline__

// Problem constants
static constexpr int BATCH = 8;
static constexpr int NPT   = 2048;
static constexpr int DMID  = 64;
static constexpr int DEMB  = 256;
static constexpr int NSA   = 4;
static constexpr long STRD = (long)DEMB * NPT;  // 524288
static constexpr long QKS  = (long)NPT * 512;   // per-batch stride of QKt
static constexpr long NN   = (long)NPT * NPT;   // 4194304

typedef __attribute__((ext_vector_type(4))) float f32x4;
typedef __attribute__((ext_vector_type(8))) short bf16x8v;

DEVI f32x4 MFMA16(bf16x8v a, bf16x8v b, f32x4 c) {
  return __builtin_amdgcn_mfma_f32_16x16x32_bf16(a, b, c, 0, 0, 0);
}

DEVI void gload16(const bf16* g, bf16* l) {
  __builtin_amdgcn_global_load_lds(
      (const __attribute__((address_space(1))) void*)g,
      (__attribute__((address_space(3))) void*)l, 16, 0, 0);
}

DEVI float waveReduceSum(float v) {
#pragma unroll
  for (int o = 32; o > 0; o >>= 1) v += __shfl_down(v, o, 64);
  return v;
}
DEVI float blockReduceSum(float v) {
  __shared__ float sm[4];
  int lane = threadIdx.x & 63, wid = threadIdx.x >> 6;
  __syncthreads();
  v = waveReduceSum(v);
  if (lane == 0) sm[wid] = v;
  __syncthreads();
  return sm[0] + sm[1] + sm[2] + sm[3];
}

// ---- fp32 -> bf16 convert ----
__global__ void k_cvt(const float* __restrict__ in, bf16* __restrict__ out, int n) {
  int i = blockIdx.x * 256 + threadIdx.x;
  if (i < n) out[i] = __float2bfloat16(in[i]);
}

// ---- concat-convert Wq,Wk -> WQKb [l][512][256] bf16 ----
__global__ void k_cvtqk(const float* __restrict__ wq, const float* __restrict__ wk,
                        bf16* __restrict__ o) {
  int idx = blockIdx.x * 256 + threadIdx.x;  // NSA*512*256
  int c = idx & 255;
  int r = (idx >> 8) & 511;
  int l = idx >> 17;
  float v = (r < 256) ? wq[((l << 8) + r) * 256 + c] : wk[((l << 8) + (r - 256)) * 256 + c];
  o[idx] = __float2bfloat16(v);
}

// ---- conv1: H1t[b][n][o] = sum_c x[b,n,c]*w1[o,c] + b1[o] ----
__global__ void k_conv1t(const float* __restrict__ x, const float* __restrict__ w1,
                         const float* __restrict__ b1, float* __restrict__ h1t) {
  long idx = (long)blockIdx.x * 256 + threadIdx.x;  // [b*n][o]
  int o = idx & 63;
  long bn = idx >> 6;
  const float* xp = x + bn * 3;
  h1t[idx] = b1[o] + xp[0] * w1[o * 3] + xp[1] * w1[o * 3 + 1] + xp[2] * w1[o * 3 + 2];
}

// ---- BN1 stats on H1t [16384][64] ----
__global__ __launch_bounds__(256) void k_bn1a(const float* __restrict__ h, float* __restrict__ pS,
                                              float* __restrict__ pS2) {
  int c = threadIdx.x & 63, rg = threadIdx.x >> 6;
  long r0 = (long)blockIdx.x * 128 + rg * 32;
  float s = 0.f, s2 = 0.f;
  for (int i = 0; i < 32; ++i) {
    float v = h[(r0 + i) * 64 + c];
    s += v; s2 += v * v;
  }
  __shared__ float smS[256], smS2[256];
  smS[threadIdx.x] = s; smS2[threadIdx.x] = s2;
  __syncthreads();
  if (threadIdx.x < 64) {
    float a = 0.f, b = 0.f;
#pragma unroll
    for (int g = 0; g < 4; ++g) { a += smS[g * 64 + c]; b += smS2[g * 64 + c]; }
    pS[blockIdx.x * 64 + c] = a;
    pS2[blockIdx.x * 64 + c] = b;
  }
}
__global__ void k_bn1b(const float* __restrict__ pS, const float* __restrict__ pS2,
                       const float* __restrict__ g, const float* __restrict__ be,
                       float* __restrict__ sa, float* __restrict__ sb) {
  int c = threadIdx.x;
  if (c >= 64) return;
  float s = 0.f, s2 = 0.f;
  for (int i = 0; i < 128; ++i) { s += pS[i * 64 + c]; s2 += pS2[i * 64 + c]; }
  const float inv = 1.0f / (BATCH * NPT);
  float m = s * inv, var = s2 * inv - m * m;
  float A = rsqrtf(var + 1e-5f) * g[c];
  sa[c] = A; sb[c] = be[c] - m * A;
}
__global__ void k_bn1apply(const float* __restrict__ h, const float* __restrict__ sa,
                           const float* __restrict__ sb, bf16* __restrict__ o) {
  long idx = (long)blockIdx.x * 256 + threadIdx.x;
  int c = idx & 63;
  float v = fmaf(h[idx], sa[c], sb[c]);
  o[idx] = __float2bfloat16(v > 0.f ? v : 0.f);
}

// ---- BN2 stats on Hn [16384][256] (per-column = per-channel) ----
__global__ __launch_bounds__(256) void k_bn2a(const float* __restrict__ h,
                                              float* __restrict__ pA, float* __restrict__ pB) {
  int c = threadIdx.x;
  long r0 = (long)blockIdx.x * 128;
  float s = 0.f, s2 = 0.f;
  for (int i = 0; i < 128; ++i) {
    float v = h[(r0 + i) * DEMB + c];
    s += v; s2 += v * v;
  }
  pA[blockIdx.x * DEMB + c] = s;
  pB[blockIdx.x * DEMB + c] = s2;
}
__global__ void k_bn2b(const float* __restrict__ pA, const float* __restrict__ pB,
                       const float* __restrict__ g, const float* __restrict__ be,
                       float* __restrict__ sa, float* __restrict__ sb) {
  int c = threadIdx.x;  // 256 threads
  float s = 0.f, s2 = 0.f;
  for (int i = 0; i < 128; ++i) { s += pA[i * DEMB + c]; s2 += pB[i * DEMB + c]; }
  const float inv = 1.0f / (BATCH * NPT);
  float m = s * inv, var = s2 * inv - m * m;
  float A = rsqrtf(var + 1e-5f) * g[c];
  sa[c] = A; sb[c] = be[c] - m * A;
}
// BN2 apply + ReLU: write Hn (f32 residual) and Htb (bf16 operand)
__global__ void k_bnapply2(float* __restrict__ hn, bf16* __restrict__ htb,
                           const float* __restrict__ sa, const float* __restrict__ sb) {
  long idx = (long)blockIdx.x * 256 + threadIdx.x;
  int c = idx & (DEMB - 1);
  float v = fmaf(hn[idx], sa[c], sb[c]);
  v = v > 0.f ? v : 0.f;
  hn[idx] = v;
  htb[idx] = __float2bfloat16(v);
}

// ---- MFMA GEMM, B^T form: C[M][N] = A[M][K] . B[N][K]^T ; 128x128 tile, BK=64 ----
// XOR-swizzled LDS (granule ^= row&7) on both staging-source and read.
// nz > 0: 1-D grid, bz = bid % nz (XCD-pin), bx = t % gx, by = t / gx.
// MODE 0: C bf16 = acc + fused column-softmax partials (PM/PS)
// MODE 2: C f32 = acc + bias[col]
template <int MODE>
__global__ __launch_bounds__(256) void k_mgemm(
    const bf16* __restrict__ A, long aStr, int ldA,
    const bf16* __restrict__ B, long bStr, int ldB,
    void* __restrict__ Cv, long cStr, int ldC,
    int K,
    const float* __restrict__ bias,
    float* __restrict__ PMo, float* __restrict__ PSo, int nz, int gx) {
  __shared__ __align__(16) bf16 sA[128 * 64];
  __shared__ __align__(16) bf16 sB[128 * 64];
  __shared__ float smx[4][64], ssx[4][64];
  int bx, by, bz;
  if (nz > 0) {
    bz = blockIdx.x % nz;
    int t = blockIdx.x / nz;
    bx = t % gx;
    by = t / gx;
  } else {
    bx = blockIdx.x; by = blockIdx.y; bz = blockIdx.z;
  }
  A += aStr * bz;
  B += bStr * bz;
  const int bm = by * 128, bn = bx * 128;
  const int tid = threadIdx.x;
  const int lane = tid & 63, wv = tid >> 6;
  const int wr = (wv >> 1) * 64, wc = (wv & 1) * 64;
  f32x4 acc[4][4] = {};

  for (int k0 = 0; k0 < K; k0 += 64) {
#pragma unroll
    for (int i = 0; i < 4; ++i) {
      int c = i * 256 + tid;
      int row = c >> 3, g = c & 7;
      int gs = (g ^ (row & 7)) * 8;
      gload16(A + (long)(bm + row) * ldA + k0 + gs, sA + c * 8);
      gload16(B + (long)(bn + row) * ldB + k0 + gs, sB + c * 8);
    }
    __syncthreads();
    bf16x8v af[4][2], bfr[4][2];
#pragma unroll
    for (int mi = 0; mi < 4; ++mi)
#pragma unroll
      for (int ks = 0; ks < 2; ++ks) {
        int rA = wr + mi * 16 + (lane & 15);
        int rB = wc + mi * 16 + (lane & 15);
        int g = ks * 4 + (lane >> 4);
        af[mi][ks]  = *(const bf16x8v*)&sA[rA * 64 + ((g ^ (rA & 7)) * 8)];
        bfr[mi][ks] = *(const bf16x8v*)&sB[rB * 64 + ((g ^ (rB & 7)) * 8)];
      }
#pragma unroll
    for (int ks = 0; ks < 2; ++ks)
#pragma unroll
      for (int mi = 0; mi < 4; ++mi)
#pragma unroll
        for (int ni = 0; ni < 4; ++ni)
          acc[mi][ni] = MFMA16(af[mi][ks], bfr[ni][ks], acc[mi][ni]);
    __syncthreads();
  }

  const int rb = (lane >> 4) * 4, cb = lane & 15;
  if constexpr (MODE == 0) {
    bf16* C = (bf16*)Cv + cStr * bz;
#pragma unroll
    for (int mi = 0; mi < 4; ++mi)
#pragma unroll
      for (int ni = 0; ni < 4; ++ni) {
        int r0 = bm + wr + mi * 16 + rb, c0 = bn + wc + ni * 16 + cb;
#pragma unroll
        for (int k = 0; k < 4; ++k)
          C[(long)(r0 + k) * ldC + c0] = __float2bfloat16(acc[mi][ni][k]);
      }
  } else {
    float* C = (float*)Cv + cStr * bz;
#pragma unroll
    for (int mi = 0; mi < 4; ++mi)
#pragma unroll
      for (int ni = 0; ni < 4; ++ni) {
        int r0 = bm + wr + mi * 16 + rb, c0 = bn + wc + ni * 16 + cb;
        float badd = bias[c0];
#pragma unroll
        for (int k = 0; k < 4; ++k) {
          int r = r0 + k;
          C[(long)r * ldC + c0] = acc[mi][ni][k] + badd;
        }
      }
  }

  if constexpr (MODE == 0) {
    // per-column (over this block's 128 rows) online-softmax partials (exact fp32)
    float cm[4], cs[4];
#pragma unroll
    for (int ni = 0; ni < 4; ++ni) {
      float m = -3.0e38f;
#pragma unroll
      for (int mi = 0; mi < 4; ++mi)
#pragma unroll
        for (int k = 0; k < 4; ++k) m = fmaxf(m, acc[mi][ni][k]);
      float s = 0.f;
#pragma unroll
      for (int mi = 0; mi < 4; ++mi)
#pragma unroll
        for (int k = 0; k < 4; ++k) s += __expf(acc[mi][ni][k] - m);
#pragma unroll
      for (int off = 16; off <= 32; off <<= 1) {
        float mo = __shfl_xor(m, off, 64);
        float so = __shfl_xor(s, off, 64);
        float M = fmaxf(m, mo);
        s = s * __expf(m - M) + so * __expf(mo - M);
        m = M;
      }
      cm[ni] = m; cs[ni] = s;
    }
    __syncthreads();  // LDS reads of K-loop complete; reuse smx/ssx safely
    if (lane < 16) {
#pragma unroll
      for (int ni = 0; ni < 4; ++ni) {
        smx[wv][ni * 16 + lane] = cm[ni];
        ssx[wv][ni * 16 + lane] = cs[ni];
      }
    }
    __syncthreads();
    if (tid < 128) {
      int half = tid >> 6, c64 = tid & 63;
      float m1 = smx[half][c64], s1 = ssx[half][c64];
      float m2 = smx[half + 2][c64], s2 = ssx[half + 2][c64];
      float M = fmaxf(m1, m2);
      float S = s1 * __expf(m1 - M) + s2 * __expf(m2 - M);
      long o = ((long)bz * 16 + by) * NPT + bn + half * 64 + c64;
      PMo[o] = M;
      PSo[o] = S;
    }
  }
}

// ---- combined QKt + V GEMM (both MODE-1-style, one launch) ----
// Slots [0,512): QKt[z][n][0..511] = Htb[z] . WQK^T (M=2048, N=512)
// Slots [512,768): Vb[z][e][n] = WV . Htb[z]^T      (M=256,  N=2048)
// Both 128x128 tiles, K=256, XCD-pinned via z = slot & 7.
__global__ __launch_bounds__(256) void k_qkv(
    const bf16* __restrict__ Htb, const bf16* __restrict__ WQK,
    const bf16* __restrict__ WV, bf16* __restrict__ QKt, bf16* __restrict__ Vb) {
  __shared__ __align__(16) bf16 sA[128 * 64];
  __shared__ __align__(16) bf16 sB[128 * 64];
  const bf16 *A, *B;
  bf16* C;
  int ldA, ldB, ldC, bm, bn;
  {
    int s = blockIdx.x;
    if (s < 512) {
      int z = s & 7, t = s >> 3;
      A = Htb + (long)z * STRD; ldA = DEMB;
      B = WQK;                  ldB = DEMB;
      C = QKt + (long)z * QKS;  ldC = 512;
      bm = (t >> 2) * 128; bn = (t & 3) * 128;
    } else {
      int s2 = s - 512;
      int z = s2 & 7, t = s2 >> 3;
      A = WV;                   ldA = DEMB;
      B = Htb + (long)z * STRD; ldB = DEMB;
      C = Vb + (long)z * STRD;  ldC = NPT;
      bm = (t >> 4) * 128; bn = (t & 15) * 128;
    }
  }
  const int tid = threadIdx.x;
  const int lane = tid & 63, wv = tid >> 6;
  const int wr = (wv >> 1) * 64, wc = (wv & 1) * 64;
  f32x4 acc[4][4] = {};

  for (int k0 = 0; k0 < DEMB; k0 += 64) {
#pragma unroll
    for (int i = 0; i < 4; ++i) {
      int c = i * 256 + tid;
      int row = c >> 3, g = c & 7;
      int gs = (g ^ (row & 7)) * 8;
      gload16(A + (long)(bm + row) * ldA + k0 + gs, sA + c * 8);
      gload16(B + (long)(bn + row) * ldB + k0 + gs, sB + c * 8);
    }
    __syncthreads();
    bf16x8v af[4][2], bfr[4][2];
#pragma unroll
    for (int mi = 0; mi < 4; ++mi)
#pragma unroll
      for (int ks = 0; ks < 2; ++ks) {
        int rA = wr + mi * 16 + (lane & 15);
        int rB = wc + mi * 16 + (lane & 15);
        int g = ks * 4 + (lane >> 4);
        af[mi][ks]  = *(const bf16x8v*)&sA[rA * 64 + ((g ^ (rA & 7)) * 8)];
        bfr[mi][ks] = *(const bf16x8v*)&sB[rB * 64 + ((g ^ (rB & 7)) * 8)];
      }
#pragma unroll
    for (int ks = 0; ks < 2; ++ks)
#pragma unroll
      for (int mi = 0; mi < 4; ++mi)
#pragma unroll
        for (int ni = 0; ni < 4; ++ni)
          acc[mi][ni] = MFMA16(af[mi][ks], bfr[ni][ks], acc[mi][ni]);
    __syncthreads();
  }

  const int rb = (lane >> 4) * 4, cb = lane & 15;
#pragma unroll
  for (int mi = 0; mi < 4; ++mi)
#pragma unroll
    for (int ni = 0; ni < 4; ++ni) {
      int r0 = bm + wr + mi * 16 + rb, c0 = bn + wc + ni * 16 + cb;
#pragma unroll
      for (int k = 0; k < 4; ++k)
        C[(long)(r0 + k) * ldC + c0] = __float2bfloat16(acc[mi][ni][k]);
    }
}

// ---- fused colstat-combine + normalize + rowsum + V.P GEMM ----
// (unchanged from R18; see comments there)
__global__ __launch_bounds__(512) void k_vp(const bf16* __restrict__ F,
                                            const float* __restrict__ PM,
                                            const float* __restrict__ PSm,
                                            const bf16* __restrict__ V,
                                            float* __restrict__ Hn,
                                            bf16* __restrict__ Htb, int nz, int wHtb) {
  __shared__ __align__(16) bf16 sA[2][256 * 64];
  __shared__ __align__(16) bf16 sB[2][64 * 64];
  __shared__ float rsLds[64][8];
  __shared__ float Sv[64];
  __shared__ float smCM[NPT], smCS[NPT];
  const int z = blockIdx.x % nz;
  const int m0 = (blockIdx.x / nz) * 64;
  const int tid = threadIdx.x;
  const int lane = tid & 63, wv = tid >> 6;
  const int we = wv & 3;
  const int wm = wv >> 2;
  const int fr = tid >> 3;
  const int fq = tid & 7;
  const bf16* Vz = V + (long)z * STRD;
  const bf16* Frp = F + (long)z * NN + (long)(m0 + fr) * NPT + fq * 8;
  f32x4 acc[4][2] = {};
  float rs = 0.f;
  bf16x8v fvA, fvB;

  {
    const float* pm = PM + (long)z * 16 * NPT;
    const float* ps = PSm + (long)z * 16 * NPT;
#pragma unroll
    for (int i = 0; i < 4; ++i) {
      int n = i * 512 + tid;
      float m = -3.0e38f;
#pragma unroll
      for (int y = 0; y < 16; ++y) m = fmaxf(m, pm[(long)y * NPT + n]);
      float s = 0.f;
#pragma unroll
      for (int y = 0; y < 16; ++y) s += ps[(long)y * NPT + n] * __expf(pm[(long)y * NPT + n] - m);
      smCM[n] = m;
      smCS[n] = 1.0f / s;
    }
  }

#define LOADF(FREG, N0) FREG = *(const bf16x8v*)(Frp + ((N0) & 2047));

#define EXPW(BUF, FREG, N0)                                                    \
  {                                                                            \
    float mv[8], cv[8];                                                        \
    *(float4*)&mv[0] = *(const float4*)&smCM[(N0) + fq * 8];                   \
    *(float4*)&mv[4] = *(const float4*)&smCM[(N0) + fq * 8 + 4];               \
    *(float4*)&cv[0] = *(const float4*)&smCS[(N0) + fq * 8];                   \
    *(float4*)&cv[4] = *(const float4*)&smCS[(N0) + fq * 8 + 4];               \
    bf16 tb[8];                                                                \
    _Pragma("unroll") for (int i = 0; i < 8; ++i) {                            \
      float fvi = __uint_as_float((unsigned)(unsigned short)FREG[i] << 16);    \
      float pv = __expf(fvi - mv[i]) * cv[i];                                  \
      rs += pv;                                                                \
      tb[i] = __float2bfloat16(pv);                                            \
    }                                                                          \
    *(bf16x8v*)&sB[BUF][fr * 64 + ((fq ^ (fr & 7)) * 8)] = *(bf16x8v*)tb;      \
  }

#define STAGEV(BUF, N0)                                                        \
  _Pragma("unroll") for (int i = 0; i < 4; ++i) {                              \
    int c = i * 512 + tid;                                                     \
    int row = c >> 3, g = c & 7;                                               \
    gload16(Vz + (long)row * NPT + ((N0) & 2047) + ((g ^ (row & 7)) * 8),      \
            &sA[BUF][c * 8]);                                                  \
  }

#define WAITBAR                                                                \
  asm volatile("s_waitcnt vmcnt(1) lgkmcnt(0)" ::: "memory");                  \
  __builtin_amdgcn_s_barrier();

  LOADF(fvA, 0)
  STAGEV(0, 0)
  __syncthreads();
  EXPW(0, fvA, 0)
  LOADF(fvB, 64)
  __syncthreads();

#define VP_BODY(CUR, FN, FN2, STEPI)                                           \
  {                                                                            \
    const int sn = (STEPI);                                                    \
    const int nn0 = sn * 64;                                                   \
    STAGEV(CUR ^ 1, nn0 + 64)                                                  \
    LOADF(FN2, nn0 + 128)                                                      \
    if (sn + 1 < 32) EXPW(CUR ^ 1, FN, nn0 + 64)                               \
    bf16x8v bfr[2][2];                                                         \
    _Pragma("unroll") for (int ni = 0; ni < 2; ++ni)                           \
      _Pragma("unroll") for (int ks = 0; ks < 2; ++ks) {                       \
        int rB = wm * 32 + ni * 16 + (lane & 15);                              \
        int g = ks * 4 + (lane >> 4);                                          \
        bfr[ni][ks] = *(const bf16x8v*)&sB[CUR][rB * 64 + ((g ^ (rB & 7)) * 8)]; \
      }                                                                        \
    _Pragma("unroll") for (int mi = 0; mi < 4; ++mi)                           \
      _Pragma("unroll") for (int ks = 0; ks < 2; ++ks) {                       \
        int rA = we * 64 + mi * 16 + (lane & 15);                              \
        int g = ks * 4 + (lane >> 4);                                          \
        bf16x8v af = *(const bf16x8v*)&sA[CUR][rA * 64 + ((g ^ (rA & 7)) * 8)]; \
        _Pragma("unroll") for (int ni = 0; ni < 2; ++ni)                       \
          acc[mi][ni] = MFMA16(af, bfr[ni][ks], acc[mi][ni]);                  \
      }                                                                        \
    WAITBAR                                                                    \
  }

  for (int it = 0; it < 16; ++it) {
    VP_BODY(0, fvB, fvA, 2 * it)
    VP_BODY(1, fvA, fvB, 2 * it + 1)
  }
#undef VP_BODY
#undef WAITBAR
#undef STAGEV
#undef EXPW
#undef LOADF

  rsLds[fr][fq] = rs;
  __syncthreads();
  if (tid < 64) {
    float R = 0.f;
#pragma unroll
    for (int q = 0; q < 8; ++q) R += rsLds[tid][q];
    Sv[tid] = 1.0f / (1e-9f + R);
  }
  __syncthreads();

  float* Hz = Hn + (long)z * STRD;
  bf16* Hb = Htb + (long)z * STRD;
  const int rb = (lane >> 4) * 4, cb = lane & 15;
#pragma unroll
  for (int mi = 0; mi < 4; ++mi) {
    int e0 = we * 64 + mi * 16 + rb;
#pragma unroll
    for (int ni = 0; ni < 2; ++ni) {
      int c = wm * 32 + ni * 16 + cb;
      float scl = Sv[c];
      long base = (long)(m0 + c) * DEMB + e0;
      float4 h = *(const float4*)(Hz + base);
      float r0 = h.x + acc[mi][ni][0] * scl;
      float r1 = h.y + acc[mi][ni][1] * scl;
      float r2 = h.z + acc[mi][ni][2] * scl;
      float r3 = h.w + acc[mi][ni][3] * scl;
      *(float4*)(Hz + base) = float4{r0, r1, r2, r3};
      if (wHtb) {
        bf16 hb[4] = {__float2bfloat16(r0), __float2bfloat16(r1),
                      __float2bfloat16(r2), __float2bfloat16(r3)};
        *(uint2*)(Hb + base) = *(uint2*)hb;
      }
    }
  }
}

// ---- pooled[b*n] = row mean of Hn [16384][256] (one wave per row) ----
__global__ void k_pool(const float* __restrict__ Hn, float* __restrict__ pooled) {
  int row = blockIdx.x * 4 + (threadIdx.x >> 6);
  int lane = threadIdx.x & 63;
  float4 v = *(const float4*)(Hn + (long)row * DEMB + lane * 4);
  float s = v.x + v.y + v.z + v.w;
  s = waveReduceSum(s);
  if (lane == 0) pooled[row] = s * (1.0f / DEMB);
}

// ---- fc1: one block per output row j; w row read ONCE, all 8 batches ----
__global__ __launch_bounds__(256) void k_fc1(const float* __restrict__ pooled,
                                             const float* __restrict__ w, const float* __restrict__ bias,
                                             float* __restrict__ f) {
  int j = blockIdx.x;
  const float* wr = w + (long)j * NPT;
  int n0 = threadIdx.x * 8;
  float wl[8];
  *(float4*)&wl[0] = *(const float4*)(wr + n0);
  *(float4*)&wl[4] = *(const float4*)(wr + n0 + 4);
  float part[8];
#pragma unroll
  for (int b = 0; b < 8; ++b) {
    const float* pp = pooled + (long)b * NPT + n0;
    float4 p0 = *(const float4*)pp, p1 = *(const float4*)(pp + 4);
    part[b] = wl[0] * p0.x + wl[1] * p0.y + wl[2] * p0.z + wl[3] * p0.w +
              wl[4] * p1.x + wl[5] * p1.y + wl[6] * p1.z + wl[7] * p1.w;
  }
#pragma unroll
  for (int b = 0; b < 8; ++b) {
    float s = blockReduceSum(part[b]);
    if (threadIdx.x == 0) {
      s += bias[j];
      f[(long)b * NPT + j] = s > 0.f ? s : 0.f;
    }
  }
}

// ---- fc2 ----
__global__ __launch_bounds__(256) void k_fc2(const float* __restrict__ f,
                                             const float* __restrict__ w, const float* __restrict__ bias,
                                             float* __restrict__ out) {
  int b = blockIdx.x;
  float s = 0.f;
  for (int j = threadIdx.x; j < NPT; j += 256) s += f[(long)b * NPT + j] * w[j];
  s = blockReduceSum(s);
  if (threadIdx.x == 0) out[b] = s + bias[0];
}

extern "C" void kernel_launch(void* const* d_in, const int* in_sizes, int n_in,
                              void* d_out, int out_size, void* d_ws, size_t ws_size,
                              hipStream_t stream) {
  const float* X    = (const float*)d_in[0];
  const float* W1   = (const float*)d_in[1];
  const float* B1   = (const float*)d_in[2];
  const float* G1   = (const float*)d_in[3];
  const float* BE1  = (const float*)d_in[4];
  const float* W2   = (const float*)d_in[5];
  const float* B2   = (const float*)d_in[6];
  const float* G2   = (const float*)d_in[7];
  const float* BE2  = (const float*)d_in[8];
  const float* WQ   = (const float*)d_in[9];
  const float* WK   = (const float*)d_in[10];
  const float* WV   = (const float*)d_in[11];
  const float* FC1W = (const float*)d_in[12];
  const float* FC1B = (const float*)d_in[13];
  const float* FC2W = (const float*)d_in[14];
  const float* FC2B = (const float*)d_in[15];
  float* OUT = (float*)d_out;

  // ---- workspace carve-out ----
  char* p = (char*)d_ws;
  auto alloc = [&](size_t bytes) -> char* {
    char* r = p;
    p += (bytes + 255) & ~(size_t)255;
    return r;
  };
  float* H1t  = (float*)alloc((size_t)BATCH * NPT * DMID * 4);
  bf16*  H1tb = (bf16*)alloc((size_t)BATCH * NPT * DMID * 2);
  float* Hn   = (float*)alloc((size_t)BATCH * STRD * 4);   // [b*n][256] f32
  bf16*  Htb  = (bf16*)alloc((size_t)BATCH * STRD * 2);    // [b*n][256] bf16
  bf16*  QKt  = (bf16*)alloc((size_t)BATCH * QKS * 2);     // [b][n][512]
  bf16*  Vb   = (bf16*)alloc((size_t)BATCH * STRD * 2);    // [b][e][n]
  bf16*  W2b  = (bf16*)alloc((size_t)DEMB * DMID * 2);
  bf16*  WQKb = (bf16*)alloc((size_t)NSA * 512 * DEMB * 2);
  bf16*  WVb  = (bf16*)alloc((size_t)NSA * DEMB * DEMB * 2);
  float* pS   = (float*)alloc(128 * 64 * 4);
  float* pS2  = (float*)alloc(128 * 64 * 4);
  float* pA2  = (float*)alloc(128 * DEMB * 4);
  float* pB2  = (float*)alloc(128 * DEMB * 4);
  float* sa1  = (float*)alloc(64 * 4);
  float* sb1  = (float*)alloc(64 * 4);
  float* sa2  = (float*)alloc(256 * 4);
  float* sb2  = (float*)alloc(256 * 4);
  float* PM   = (float*)alloc((size_t)BATCH * 16 * NPT * 4);
  float* PSm  = (float*)alloc((size_t)BATCH * 16 * NPT * 4);
  float* POOL = (float*)alloc((size_t)BATCH * NPT * 4);
  float* FH   = (float*)alloc((size_t)BATCH * NPT * 4);
  size_t used = (size_t)(p - (char*)d_ws);
  const size_t per_g = (size_t)NN * 2;  // F bf16 (8MB per batch)
  int G = 8;
  while (G > 1 && used + (size_t)G * per_g + 1024 > ws_size) G >>= 1;
  bf16* F = (bf16*)alloc((size_t)G * NN * 2);

  // ---- weight converts ----
  k_cvt<<<(DEMB * DMID + 255) / 256, 256, 0, stream>>>(W2, W2b, DEMB * DMID);
  int nqk = NSA * 512 * DEMB;
  k_cvtqk<<<nqk / 256, 256, 0, stream>>>(WQ, WK, WQKb);
  int nw = NSA * DEMB * DEMB;
  k_cvt<<<(nw + 255) / 256, 256, 0, stream>>>(WV, WVb, nw);

  // ---- conv1 + BN1 + ReLU (-> H1tb bf16 [b*n][64]) ----
  long szh1 = (long)BATCH * NPT * DMID;
  k_conv1t<<<(int)(szh1 / 256), 256, 0, stream>>>(X, W1, B1, H1t);
  k_bn1a<<<128, 256, 0, stream>>>(H1t, pS, pS2);
  k_bn1b<<<1, 64, 0, stream>>>(pS, pS2, G1, BE1, sa1, sb1);
  k_bn1apply<<<(int)(szh1 / 256), 256, 0, stream>>>(H1t, sa1, sb1, H1tb);

  // ---- conv2 (MFMA, [n][e] layout) + BN2 + ReLU -> Hn f32 + Htb bf16 ----
  k_mgemm<2><<<dim3(2, 128, 1), 256, 0, stream>>>(H1tb, 0, DMID, W2b, 0, DMID,
                                                  Hn, 0, DEMB, DMID, B2, nullptr, nullptr, 0, 0);
  k_bn2a<<<128, 256, 0, stream>>>(Hn, pA2, pB2);
  k_bn2b<<<1, 256, 0, stream>>>(pA2, pB2, G2, BE2, sa2, sb2);
  k_bnapply2<<<(int)(BATCH * STRD / 256), 256, 0, stream>>>(Hn, Htb, sa2, sb2);

  // ---- SA layers (batch b pinned to XCD b across the whole chain) ----
  for (int l = 0; l < NSA; ++l) {
    // fused QKt + V projections (one launch, 768 blocks)
    k_qkv<<<dim3(768), 256, 0, stream>>>(Htb, WQKb + (long)l * 512 * DEMB,
                                         WVb + (long)l * DEMB * DEMB, QKt, Vb);
    for (int b0 = 0; b0 < BATCH; b0 += G) {
      // F[m][n] = sum_a Kt[m][a] Qt[n][a] (= E^T), bf16 + fused exact column stats
      k_mgemm<0><<<dim3(256 * G), 256, 0, stream>>>(QKt + 256 + b0 * QKS, QKS, 512,
                                                    QKt + b0 * QKS, QKS, 512,
                                                    F, NN, NPT, DEMB, nullptr, PM, PSm, G, 16);
      // Hn[m][e] += S[m] * sum_n V[e][n] PT[m][n]; Htb = bf16(Hn) (not last layer)
      k_vp<<<dim3(32 * G), 512, 0, stream>>>(F, PM, PSm, Vb + b0 * STRD,
                                             Hn + b0 * STRD, Htb + b0 * STRD, G,
                                             (l < NSA - 1) ? 1 : 0);
    }
  }

  // ---- head ----
  k_pool<<<(BATCH * NPT) / 4, 256, 0, stream>>>(Hn, POOL);
  k_fc1<<<NPT, 256, 0, stream>>>(POOL, FC1W, FC1B, FH);
  k_fc2<<<BATCH, 256, 0, stream>>>(FH, FC2W, FC2B, OUT);
}

// Round 20
// 385.909 us; speedup vs baseline: 1.1305x; 1.0393x over previous
//
#include <hip/hip_runtime.h>
#include <hip/hip_bf16.h>

typedef __hip_bfloat16 bf16;
#define DEVI __device__ __forceinline__

// Problem constants
static constexpr int BATCH = 8;
static constexpr int NPT   = 2048;
static constexpr int DMID  = 64;
static constexpr int DEMB  = 256;
static constexpr int NSA   = 4;
static constexpr long STRD = (long)DEMB * NPT;  // 524288
static constexpr long QKS  = (long)NPT * 512;   // per-batch stride of QKt
static constexpr long NN   = (long)NPT * NPT;   // 4194304

typedef __attribute__((ext_vector_type(4))) float f32x4;
typedef __attribute__((ext_vector_type(8))) short bf16x8v;

DEVI f32x4 MFMA16(bf16x8v a, bf16x8v b, f32x4 c) {
  return __builtin_amdgcn_mfma_f32_16x16x32_bf16(a, b, c, 0, 0, 0);
}

DEVI void gload16(const bf16* g, bf16* l) {
  __builtin_amdgcn_global_load_lds(
      (const __attribute__((address_space(1))) void*)g,
      (__attribute__((address_space(3))) void*)l, 16, 0, 0);
}

DEVI float waveReduceSum(float v) {
#pragma unroll
  for (int o = 32; o > 0; o >>= 1) v += __shfl_down(v, o, 64);
  return v;
}
DEVI float blockReduceSum(float v) {
  __shared__ float sm[4];
  int lane = threadIdx.x & 63, wid = threadIdx.x >> 6;
  __syncthreads();
  v = waveReduceSum(v);
  if (lane == 0) sm[wid] = v;
  __syncthreads();
  return sm[0] + sm[1] + sm[2] + sm[3];
}

// ---- fused weight converts: W2 | [Wq;Wk] concat | Wv ----
__global__ void k_cvtall(const float* __restrict__ w2, const float* __restrict__ wq,
                         const float* __restrict__ wk, const float* __restrict__ wv,
                         bf16* __restrict__ W2b, bf16* __restrict__ WQKb,
                         bf16* __restrict__ WVb) {
  int idx = blockIdx.x * 256 + threadIdx.x;
  if (idx < DEMB * DMID) {
    W2b[idx] = __float2bfloat16(w2[idx]);
  } else if (idx < DEMB * DMID + NSA * 512 * DEMB) {
    int i = idx - DEMB * DMID;
    int c = i & 255;
    int r = (i >> 8) & 511;
    int l = i >> 17;
    float v = (r < 256) ? wq[((l << 8) + r) * 256 + c] : wk[((l << 8) + (r - 256)) * 256 + c];
    WQKb[i] = __float2bfloat16(v);
  } else {
    int i = idx - (DEMB * DMID + NSA * 512 * DEMB);
    if (i < NSA * DEMB * DEMB) WVb[i] = __float2bfloat16(wv[i]);
  }
}

// ---- conv1: H1t[b][n][o] = sum_c x[b,n,c]*w1[o,c] + b1[o] ----
__global__ void k_conv1t(const float* __restrict__ x, const float* __restrict__ w1,
                         const float* __restrict__ b1, float* __restrict__ h1t) {
  long idx = (long)blockIdx.x * 256 + threadIdx.x;  // [b*n][o]
  int o = idx & 63;
  long bn = idx >> 6;
  const float* xp = x + bn * 3;
  h1t[idx] = b1[o] + xp[0] * w1[o * 3] + xp[1] * w1[o * 3 + 1] + xp[2] * w1[o * 3 + 2];
}

// ---- BN1 stats on H1t [16384][64] ----
__global__ __launch_bounds__(256) void k_bn1a(const float* __restrict__ h, float* __restrict__ pS,
                                              float* __restrict__ pS2) {
  int c = threadIdx.x & 63, rg = threadIdx.x >> 6;
  long r0 = (long)blockIdx.x * 128 + rg * 32;
  float s = 0.f, s2 = 0.f;
  for (int i = 0; i < 32; ++i) {
    float v = h[(r0 + i) * 64 + c];
    s += v; s2 += v * v;
  }
  __shared__ float smS[256], smS2[256];
  smS[threadIdx.x] = s; smS2[threadIdx.x] = s2;
  __syncthreads();
  if (threadIdx.x < 64) {
    float a = 0.f, b = 0.f;
#pragma unroll
    for (int g = 0; g < 4; ++g) { a += smS[g * 64 + c]; b += smS2[g * 64 + c]; }
    pS[blockIdx.x * 64 + c] = a;
    pS2[blockIdx.x * 64 + c] = b;
  }
}
__global__ void k_bn1b(const float* __restrict__ pS, const float* __restrict__ pS2,
                       const float* __restrict__ g, const float* __restrict__ be,
                       float* __restrict__ sa, float* __restrict__ sb) {
  int c = threadIdx.x;
  if (c >= 64) return;
  float s = 0.f, s2 = 0.f;
  for (int i = 0; i < 128; ++i) { s += pS[i * 64 + c]; s2 += pS2[i * 64 + c]; }
  const float inv = 1.0f / (BATCH * NPT);
  float m = s * inv, var = s2 * inv - m * m;
  float A = rsqrtf(var + 1e-5f) * g[c];
  sa[c] = A; sb[c] = be[c] - m * A;
}
__global__ void k_bn1apply(const float* __restrict__ h, const float* __restrict__ sa,
                           const float* __restrict__ sb, bf16* __restrict__ o) {
  long idx = (long)blockIdx.x * 256 + threadIdx.x;
  int c = idx & 63;
  float v = fmaf(h[idx], sa[c], sb[c]);
  o[idx] = __float2bfloat16(v > 0.f ? v : 0.f);
}

// ---- BN2 combine (partials from conv2 epilogue) ----
__global__ void k_bn2b(const float* __restrict__ pA, const float* __restrict__ pB,
                       const float* __restrict__ g, const float* __restrict__ be,
                       float* __restrict__ sa, float* __restrict__ sb) {
  int c = threadIdx.x;  // 256 threads
  float s = 0.f, s2 = 0.f;
  for (int i = 0; i < 128; ++i) { s += pA[i * DEMB + c]; s2 += pB[i * DEMB + c]; }
  const float inv = 1.0f / (BATCH * NPT);
  float m = s * inv, var = s2 * inv - m * m;
  float A = rsqrtf(var + 1e-5f) * g[c];
  sa[c] = A; sb[c] = be[c] - m * A;
}
// BN2 apply + ReLU: write Hn (f32 residual) and Htb (bf16 operand)
__global__ void k_bnapply2(float* __restrict__ hn, bf16* __restrict__ htb,
                           const float* __restrict__ sa, const float* __restrict__ sb) {
  long idx = (long)blockIdx.x * 256 + threadIdx.x;
  int c = idx & (DEMB - 1);
  float v = fmaf(hn[idx], sa[c], sb[c]);
  v = v > 0.f ? v : 0.f;
  hn[idx] = v;
  htb[idx] = __float2bfloat16(v);
}

// ---- MFMA GEMM, B^T form: C[M][N] = A[M][K] . B[N][K]^T ; 128x128 tile, BK=64 ----
// XOR-swizzled LDS (granule ^= row&7) on both staging-source and read.
// nz > 0: 1-D grid, bz = bid % nz (XCD-pin), bx = t % gx, by = t / gx.
// MODE 0: C bf16 = acc + fused column-softmax partials (PM/PS)
// MODE 2: C f32 = acc + bias[col] + fused column sum/sumsq partials (PM/PS)
template <int MODE>
__global__ __launch_bounds__(256) void k_mgemm(
    const bf16* __restrict__ A, long aStr, int ldA,
    const bf16* __restrict__ B, long bStr, int ldB,
    void* __restrict__ Cv, long cStr, int ldC,
    int K,
    const float* __restrict__ bias,
    float* __restrict__ PMo, float* __restrict__ PSo, int nz, int gx) {
  __shared__ __align__(16) bf16 sA[128 * 64];
  __shared__ __align__(16) bf16 sB[128 * 64];
  __shared__ float smx[4][64], ssx[4][64];
  int bx, by, bz;
  if (nz > 0) {
    bz = blockIdx.x % nz;
    int t = blockIdx.x / nz;
    bx = t % gx;
    by = t / gx;
  } else {
    bx = blockIdx.x; by = blockIdx.y; bz = blockIdx.z;
  }
  A += aStr * bz;
  B += bStr * bz;
  const int bm = by * 128, bn = bx * 128;
  const int tid = threadIdx.x;
  const int lane = tid & 63, wv = tid >> 6;
  const int wr = (wv >> 1) * 64, wc = (wv & 1) * 64;
  f32x4 acc[4][4] = {};

  for (int k0 = 0; k0 < K; k0 += 64) {
#pragma unroll
    for (int i = 0; i < 4; ++i) {
      int c = i * 256 + tid;
      int row = c >> 3, g = c & 7;
      int gs = (g ^ (row & 7)) * 8;
      gload16(A + (long)(bm + row) * ldA + k0 + gs, sA + c * 8);
      gload16(B + (long)(bn + row) * ldB + k0 + gs, sB + c * 8);
    }
    __syncthreads();
    bf16x8v af[4][2], bfr[4][2];
#pragma unroll
    for (int mi = 0; mi < 4; ++mi)
#pragma unroll
      for (int ks = 0; ks < 2; ++ks) {
        int rA = wr + mi * 16 + (lane & 15);
        int rB = wc + mi * 16 + (lane & 15);
        int g = ks * 4 + (lane >> 4);
        af[mi][ks]  = *(const bf16x8v*)&sA[rA * 64 + ((g ^ (rA & 7)) * 8)];
        bfr[mi][ks] = *(const bf16x8v*)&sB[rB * 64 + ((g ^ (rB & 7)) * 8)];
      }
#pragma unroll
    for (int ks = 0; ks < 2; ++ks)
#pragma unroll
      for (int mi = 0; mi < 4; ++mi)
#pragma unroll
        for (int ni = 0; ni < 4; ++ni)
          acc[mi][ni] = MFMA16(af[mi][ks], bfr[ni][ks], acc[mi][ni]);
    __syncthreads();
  }

  const int rb = (lane >> 4) * 4, cb = lane & 15;
  float st_s[4] = {}, st_q[4] = {};
  if constexpr (MODE == 0) {
    bf16* C = (bf16*)Cv + cStr * bz;
#pragma unroll
    for (int mi = 0; mi < 4; ++mi)
#pragma unroll
      for (int ni = 0; ni < 4; ++ni) {
        int r0 = bm + wr + mi * 16 + rb, c0 = bn + wc + ni * 16 + cb;
#pragma unroll
        for (int k = 0; k < 4; ++k)
          C[(long)(r0 + k) * ldC + c0] = __float2bfloat16(acc[mi][ni][k]);
      }
  } else {
    float* C = (float*)Cv + cStr * bz;
#pragma unroll
    for (int mi = 0; mi < 4; ++mi)
#pragma unroll
      for (int ni = 0; ni < 4; ++ni) {
        int r0 = bm + wr + mi * 16 + rb, c0 = bn + wc + ni * 16 + cb;
        float badd = bias[c0];
#pragma unroll
        for (int k = 0; k < 4; ++k) {
          int r = r0 + k;
          float v = acc[mi][ni][k] + badd;
          C[(long)r * ldC + c0] = v;
          st_s[ni] += v;
          st_q[ni] += v * v;
        }
      }
  }

  if constexpr (MODE == 0) {
    // per-column (over this block's 128 rows) online-softmax partials (exact fp32)
    float cm[4], cs[4];
#pragma unroll
    for (int ni = 0; ni < 4; ++ni) {
      float m = -3.0e38f;
#pragma unroll
      for (int mi = 0; mi < 4; ++mi)
#pragma unroll
        for (int k = 0; k < 4; ++k) m = fmaxf(m, acc[mi][ni][k]);
      float s = 0.f;
#pragma unroll
      for (int mi = 0; mi < 4; ++mi)
#pragma unroll
        for (int k = 0; k < 4; ++k) s += __expf(acc[mi][ni][k] - m);
#pragma unroll
      for (int off = 16; off <= 32; off <<= 1) {
        float mo = __shfl_xor(m, off, 64);
        float so = __shfl_xor(s, off, 64);
        float M = fmaxf(m, mo);
        s = s * __expf(m - M) + so * __expf(mo - M);
        m = M;
      }
      cm[ni] = m; cs[ni] = s;
    }
    __syncthreads();
    if (lane < 16) {
#pragma unroll
      for (int ni = 0; ni < 4; ++ni) {
        smx[wv][ni * 16 + lane] = cm[ni];
        ssx[wv][ni * 16 + lane] = cs[ni];
      }
    }
    __syncthreads();
    if (tid < 128) {
      int half = tid >> 6, c64 = tid & 63;
      float m1 = smx[half][c64], s1 = ssx[half][c64];
      float m2 = smx[half + 2][c64], s2 = ssx[half + 2][c64];
      float M = fmaxf(m1, m2);
      float S = s1 * __expf(m1 - M) + s2 * __expf(m2 - M);
      long o = ((long)bz * 16 + by) * NPT + bn + half * 64 + c64;
      PMo[o] = M;
      PSo[o] = S;
    }
  } else {
    // fused BN partials: per-column sum/sumsq over this block's 128 rows
#pragma unroll
    for (int ni = 0; ni < 4; ++ni) {
#pragma unroll
      for (int off = 16; off <= 32; off <<= 1) {
        st_s[ni] += __shfl_xor(st_s[ni], off, 64);
        st_q[ni] += __shfl_xor(st_q[ni], off, 64);
      }
    }
    __syncthreads();
    if (lane < 16) {
#pragma unroll
      for (int ni = 0; ni < 4; ++ni) {
        smx[wv][ni * 16 + lane] = st_s[ni];
        ssx[wv][ni * 16 + lane] = st_q[ni];
      }
    }
    __syncthreads();
    if (tid < 128) {
      int half = tid >> 6, c64 = tid & 63;
      float S = smx[half][c64] + smx[half + 2][c64];
      float Q = ssx[half][c64] + ssx[half + 2][c64];
      int col = bn + half * 64 + c64;
      PMo[by * DEMB + col] = S;
      PSo[by * DEMB + col] = Q;
    }
  }
}

// ---- combined QKt + V GEMM (one launch) ----
// Slots [0,512): QKt[z][n][0..511] = Htb[z] . WQK^T (M=2048, N=512)
// Slots [512,768): Vb[z][e][n] = WV . Htb[z]^T      (M=256,  N=2048)
__global__ __launch_bounds__(256) void k_qkv(
    const bf16* __restrict__ Htb, const bf16* __restrict__ WQK,
    const bf16* __restrict__ WV, bf16* __restrict__ QKt, bf16* __restrict__ Vb) {
  __shared__ __align__(16) bf16 sA[128 * 64];
  __shared__ __align__(16) bf16 sB[128 * 64];
  const bf16 *A, *B;
  bf16* C;
  int ldA, ldB, ldC, bm, bn;
  {
    int s = blockIdx.x;
    if (s < 512) {
      int z = s & 7, t = s >> 3;
      A = Htb + (long)z * STRD; ldA = DEMB;
      B = WQK;                  ldB = DEMB;
      C = QKt + (long)z * QKS;  ldC = 512;
      bm = (t >> 2) * 128; bn = (t & 3) * 128;
    } else {
      int s2 = s - 512;
      int z = s2 & 7, t = s2 >> 3;
      A = WV;                   ldA = DEMB;
      B = Htb + (long)z * STRD; ldB = DEMB;
      C = Vb + (long)z * STRD;  ldC = NPT;
      bm = (t >> 4) * 128; bn = (t & 15) * 128;
    }
  }
  const int tid = threadIdx.x;
  const int lane = tid & 63, wv = tid >> 6;
  const int wr = (wv >> 1) * 64, wc = (wv & 1) * 64;
  f32x4 acc[4][4] = {};

  for (int k0 = 0; k0 < DEMB; k0 += 64) {
#pragma unroll
    for (int i = 0; i < 4; ++i) {
      int c = i * 256 + tid;
      int row = c >> 3, g = c & 7;
      int gs = (g ^ (row & 7)) * 8;
      gload16(A + (long)(bm + row) * ldA + k0 + gs, sA + c * 8);
      gload16(B + (long)(bn + row) * ldB + k0 + gs, sB + c * 8);
    }
    __syncthreads();
    bf16x8v af[4][2], bfr[4][2];
#pragma unroll
    for (int mi = 0; mi < 4; ++mi)
#pragma unroll
      for (int ks = 0; ks < 2; ++ks) {
        int rA = wr + mi * 16 + (lane & 15);
        int rB = wc + mi * 16 + (lane & 15);
        int g = ks * 4 + (lane >> 4);
        af[mi][ks]  = *(const bf16x8v*)&sA[rA * 64 + ((g ^ (rA & 7)) * 8)];
        bfr[mi][ks] = *(const bf16x8v*)&sB[rB * 64 + ((g ^ (rB & 7)) * 8)];
      }
#pragma unroll
    for (int ks = 0; ks < 2; ++ks)
#pragma unroll
      for (int mi = 0; mi < 4; ++mi)
#pragma unroll
        for (int ni = 0; ni < 4; ++ni)
          acc[mi][ni] = MFMA16(af[mi][ks], bfr[ni][ks], acc[mi][ni]);
    __syncthreads();
  }

  const int rb = (lane >> 4) * 4, cb = lane & 15;
#pragma unroll
  for (int mi = 0; mi < 4; ++mi)
#pragma unroll
    for (int ni = 0; ni < 4; ++ni) {
      int r0 = bm + wr + mi * 16 + rb, c0 = bn + wc + ni * 16 + cb;
#pragma unroll
      for (int k = 0; k < 4; ++k)
        C[(long)(r0 + k) * ldC + c0] = __float2bfloat16(acc[mi][ni][k]);
    }
}

// ---- fused colstat-combine + normalize + rowsum + V.P GEMM ----
// wHtb=1: Hn += delta, Htb = bf16(Hn). wHtb=0 (last layer): no Hn/Htb
// writes; instead POOL[z*NPT + m] = rowmean_e(Hn + delta).
__global__ __launch_bounds__(512) void k_vp(const bf16* __restrict__ F,
                                            const float* __restrict__ PM,
                                            const float* __restrict__ PSm,
                                            const bf16* __restrict__ V,
                                            float* __restrict__ Hn,
                                            bf16* __restrict__ Htb,
                                            float* __restrict__ POOL, int nz, int wHtb) {
  __shared__ __align__(16) bf16 sA[2][256 * 64];
  __shared__ __align__(16) bf16 sB[2][64 * 64];
  __shared__ float rsLds[64][8];
  __shared__ float Sv[64];
  __shared__ float psum[8][32];
  __shared__ float smCM[NPT], smCS[NPT];
  const int z = blockIdx.x % nz;
  const int m0 = (blockIdx.x / nz) * 64;
  const int tid = threadIdx.x;
  const int lane = tid & 63, wv = tid >> 6;
  const int we = wv & 3;
  const int wm = wv >> 2;
  const int fr = tid >> 3;
  const int fq = tid & 7;
  const bf16* Vz = V + (long)z * STRD;
  const bf16* Frp = F + (long)z * NN + (long)(m0 + fr) * NPT + fq * 8;
  f32x4 acc[4][2] = {};
  float rs = 0.f;
  bf16x8v fvA, fvB;

  {
    const float* pm = PM + (long)z * 16 * NPT;
    const float* ps = PSm + (long)z * 16 * NPT;
#pragma unroll
    for (int i = 0; i < 4; ++i) {
      int n = i * 512 + tid;
      float m = -3.0e38f;
#pragma unroll
      for (int y = 0; y < 16; ++y) m = fmaxf(m, pm[(long)y * NPT + n]);
      float s = 0.f;
#pragma unroll
      for (int y = 0; y < 16; ++y) s += ps[(long)y * NPT + n] * __expf(pm[(long)y * NPT + n] - m);
      smCM[n] = m;
      smCS[n] = 1.0f / s;
    }
  }

#define LOADF(FREG, N0) FREG = *(const bf16x8v*)(Frp + ((N0) & 2047));

#define EXPW(BUF, FREG, N0)                                                    \
  {                                                                            \
    float mv[8], cv[8];                                                        \
    *(float4*)&mv[0] = *(const float4*)&smCM[(N0) + fq * 8];                   \
    *(float4*)&mv[4] = *(const float4*)&smCM[(N0) + fq * 8 + 4];               \
    *(float4*)&cv[0] = *(const float4*)&smCS[(N0) + fq * 8];                   \
    *(float4*)&cv[4] = *(const float4*)&smCS[(N0) + fq * 8 + 4];               \
    bf16 tb[8];                                                                \
    _Pragma("unroll") for (int i = 0; i < 8; ++i) {                            \
      float fvi = __uint_as_float((unsigned)(unsigned short)FREG[i] << 16);    \
      float pv = __expf(fvi - mv[i]) * cv[i];                                  \
      rs += pv;                                                                \
      tb[i] = __float2bfloat16(pv);                                            \
    }                                                                          \
    *(bf16x8v*)&sB[BUF][fr * 64 + ((fq ^ (fr & 7)) * 8)] = *(bf16x8v*)tb;      \
  }

#define STAGEV(BUF, N0)                                                        \
  _Pragma("unroll") for (int i = 0; i < 4; ++i) {                              \
    int c = i * 512 + tid;                                                     \
    int row = c >> 3, g = c & 7;                                               \
    gload16(Vz + (long)row * NPT + ((N0) & 2047) + ((g ^ (row & 7)) * 8),      \
            &sA[BUF][c * 8]);                                                  \
  }

#define WAITBAR                                                                \
  asm volatile("s_waitcnt vmcnt(1) lgkmcnt(0)" ::: "memory");                  \
  __builtin_amdgcn_s_barrier();

  LOADF(fvA, 0)
  STAGEV(0, 0)
  __syncthreads();
  EXPW(0, fvA, 0)
  LOADF(fvB, 64)
  __syncthreads();

#define VP_BODY(CUR, FN, FN2, STEPI)                                           \
  {                                                                            \
    const int sn = (STEPI);                                                    \
    const int nn0 = sn * 64;                                                   \
    STAGEV(CUR ^ 1, nn0 + 64)                                                  \
    LOADF(FN2, nn0 + 128)                                                      \
    if (sn + 1 < 32) EXPW(CUR ^ 1, FN, nn0 + 64)                               \
    bf16x8v bfr[2][2];                                                         \
    _Pragma("unroll") for (int ni = 0; ni < 2; ++ni)                           \
      _Pragma("unroll") for (int ks = 0; ks < 2; ++ks) {                       \
        int rB = wm * 32 + ni * 16 + (lane & 15);                              \
        int g = ks * 4 + (lane >> 4);                                          \
        bfr[ni][ks] = *(const bf16x8v*)&sB[CUR][rB * 64 + ((g ^ (rB & 7)) * 8)]; \
      }                                                                        \
    _Pragma("unroll") for (int mi = 0; mi < 4; ++mi)                           \
      _Pragma("unroll") for (int ks = 0; ks < 2; ++ks) {                       \
        int rA = we * 64 + mi * 16 + (lane & 15);                              \
        int g = ks * 4 + (lane >> 4);                                          \
        bf16x8v af = *(const bf16x8v*)&sA[CUR][rA * 64 + ((g ^ (rA & 7)) * 8)]; \
        _Pragma("unroll") for (int ni = 0; ni < 2; ++ni)                       \
          acc[mi][ni] = MFMA16(af, bfr[ni][ks], acc[mi][ni]);                  \
      }                                                                        \
    WAITBAR                                                                    \
  }

  for (int it = 0; it < 16; ++it) {
    VP_BODY(0, fvB, fvA, 2 * it)
    VP_BODY(1, fvA, fvB, 2 * it + 1)
  }
#undef VP_BODY
#undef WAITBAR
#undef STAGEV
#undef EXPW
#undef LOADF

  rsLds[fr][fq] = rs;
  __syncthreads();
  if (tid < 64) {
    float R = 0.f;
#pragma unroll
    for (int q = 0; q < 8; ++q) R += rsLds[tid][q];
    Sv[tid] = 1.0f / (1e-9f + R);
  }
  __syncthreads();

  float* Hz = Hn + (long)z * STRD;
  bf16* Hb = Htb + (long)z * STRD;
  const int rb = (lane >> 4) * 4, cb = lane & 15;
  float csum[2] = {0.f, 0.f};
#pragma unroll
  for (int mi = 0; mi < 4; ++mi) {
    int e0 = we * 64 + mi * 16 + rb;
#pragma unroll
    for (int ni = 0; ni < 2; ++ni) {
      int c = wm * 32 + ni * 16 + cb;
      float scl = Sv[c];
      long base = (long)(m0 + c) * DEMB + e0;
      float4 h = *(const float4*)(Hz + base);
      float r0 = h.x + acc[mi][ni][0] * scl;
      float r1 = h.y + acc[mi][ni][1] * scl;
      float r2 = h.z + acc[mi][ni][2] * scl;
      float r3 = h.w + acc[mi][ni][3] * scl;
      if (wHtb) {
        *(float4*)(Hz + base) = float4{r0, r1, r2, r3};
        bf16 hb[4] = {__float2bfloat16(r0), __float2bfloat16(r1),
                      __float2bfloat16(r2), __float2bfloat16(r3)};
        *(uint2*)(Hb + base) = *(uint2*)hb;
      }
      csum[ni] += (r0 + r1) + (r2 + r3);
    }
  }

  if (!wHtb) {
    // pooled row means: reduce csum over rb-groups, then over e-quarters (we)
#pragma unroll
    for (int ni = 0; ni < 2; ++ni) {
      float s = csum[ni];
      s += __shfl_down(s, 16, 64);
      s += __shfl_down(s, 32, 64);
      if (lane < 16) psum[wv][ni * 16 + lane] = s;
    }
    __syncthreads();
    if (tid < 64) {
      int wmq = tid >> 5, cl = tid & 31;
      float s = psum[wmq * 4 + 0][cl] + psum[wmq * 4 + 1][cl] +
                psum[wmq * 4 + 2][cl] + psum[wmq * 4 + 3][cl];
      POOL[(long)z * NPT + m0 + wmq * 32 + cl] = s * (1.0f / DEMB);
    }
  }
}

// ---- fc1: one block per output row j; w row read ONCE, all 8 batches ----
__global__ __launch_bounds__(256) void k_fc1(const float* __restrict__ pooled,
                                             const float* __restrict__ w, const float* __restrict__ bias,
                                             float* __restrict__ f) {
  int j = blockIdx.x;
  const float* wr = w + (long)j * NPT;
  int n0 = threadIdx.x * 8;
  float wl[8];
  *(float4*)&wl[0] = *(const float4*)(wr + n0);
  *(float4*)&wl[4] = *(const float4*)(wr + n0 + 4);
  float part[8];
#pragma unroll
  for (int b = 0; b < 8; ++b) {
    const float* pp = pooled + (long)b * NPT + n0;
    float4 p0 = *(const float4*)pp, p1 = *(const float4*)(pp + 4);
    part[b] = wl[0] * p0.x + wl[1] * p0.y + wl[2] * p0.z + wl[3] * p0.w +
              wl[4] * p1.x + wl[5] * p1.y + wl[6] * p1.z + wl[7] * p1.w;
  }
#pragma unroll
  for (int b = 0; b < 8; ++b) {
    float s = blockReduceSum(part[b]);
    if (threadIdx.x == 0) {
      s += bias[j];
      f[(long)b * NPT + j] = s > 0.f ? s : 0.f;
    }
  }
}

// ---- fc2 ----
__global__ __launch_bounds__(256) void k_fc2(const float* __restrict__ f,
                                             const float* __restrict__ w, const float* __restrict__ bias,
                                             float* __restrict__ out) {
  int b = blockIdx.x;
  float s = 0.f;
  for (int j = threadIdx.x; j < NPT; j += 256) s += f[(long)b * NPT + j] * w[j];
  s = blockReduceSum(s);
  if (threadIdx.x == 0) out[b] = s + bias[0];
}

extern "C" void kernel_launch(void* const* d_in, const int* in_sizes, int n_in,
                              void* d_out, int out_size, void* d_ws, size_t ws_size,
                              hipStream_t stream) {
  const float* X    = (const float*)d_in[0];
  const float* W1   = (const float*)d_in[1];
  const float* B1   = (const float*)d_in[2];
  const float* G1   = (const float*)d_in[3];
  const float* BE1  = (const float*)d_in[4];
  const float* W2   = (const float*)d_in[5];
  const float* B2   = (const float*)d_in[6];
  const float* G2   = (const float*)d_in[7];
  const float* BE2  = (const float*)d_in[8];
  const float* WQ   = (const float*)d_in[9];
  const float* WK   = (const float*)d_in[10];
  const float* WV   = (const float*)d_in[11];
  const float* FC1W = (const float*)d_in[12];
  const float* FC1B = (const float*)d_in[13];
  const float* FC2W = (const float*)d_in[14];
  const float* FC2B = (const float*)d_in[15];
  float* OUT = (float*)d_out;

  // ---- workspace carve-out ----
  char* p = (char*)d_ws;
  auto alloc = [&](size_t bytes) -> char* {
    char* r = p;
    p += (bytes + 255) & ~(size_t)255;
    return r;
  };
  float* H1t  = (float*)alloc((size_t)BATCH * NPT * DMID * 4);
  bf16*  H1tb = (bf16*)alloc((size_t)BATCH * NPT * DMID * 2);
  float* Hn   = (float*)alloc((size_t)BATCH * STRD * 4);   // [b*n][256] f32
  bf16*  Htb  = (bf16*)alloc((size_t)BATCH * STRD * 2);    // [b*n][256] bf16
  bf16*  QKt  = (bf16*)alloc((size_t)BATCH * QKS * 2);     // [b][n][512]
  bf16*  Vb   = (bf16*)alloc((size_t)BATCH * STRD * 2);    // [b][e][n]
  bf16*  W2b  = (bf16*)alloc((size_t)DEMB * DMID * 2);
  bf16*  WQKb = (bf16*)alloc((size_t)NSA * 512 * DEMB * 2);
  bf16*  WVb  = (bf16*)alloc((size_t)NSA * DEMB * DEMB * 2);
  float* pS   = (float*)alloc(128 * 64 * 4);
  float* pS2  = (float*)alloc(128 * 64 * 4);
  float* pA2  = (float*)alloc(128 * DEMB * 4);
  float* pB2  = (float*)alloc(128 * DEMB * 4);
  float* sa1  = (float*)alloc(64 * 4);
  float* sb1  = (float*)alloc(64 * 4);
  float* sa2  = (float*)alloc(256 * 4);
  float* sb2  = (float*)alloc(256 * 4);
  float* PM   = (float*)alloc((size_t)BATCH * 16 * NPT * 4);
  float* PSm  = (float*)alloc((size_t)BATCH * 16 * NPT * 4);
  float* POOL = (float*)alloc((size_t)BATCH * NPT * 4);
  float* FH   = (float*)alloc((size_t)BATCH * NPT * 4);
  size_t used = (size_t)(p - (char*)d_ws);
  const size_t per_g = (size_t)NN * 2;  // F bf16 (8MB per batch)
  int G = 8;
  while (G > 1 && used + (size_t)G * per_g + 1024 > ws_size) G >>= 1;
  bf16* F = (bf16*)alloc((size_t)G * NN * 2);

  // ---- fused weight converts (one launch) ----
  int ncv = DEMB * DMID + NSA * 512 * DEMB + NSA * DEMB * DEMB;
  k_cvtall<<<(ncv + 255) / 256, 256, 0, stream>>>(W2, WQ, WK, WV, W2b, WQKb, WVb);

  // ---- conv1 + BN1 + ReLU (-> H1tb bf16 [b*n][64]) ----
  long szh1 = (long)BATCH * NPT * DMID;
  k_conv1t<<<(int)(szh1 / 256), 256, 0, stream>>>(X, W1, B1, H1t);
  k_bn1a<<<128, 256, 0, stream>>>(H1t, pS, pS2);
  k_bn1b<<<1, 64, 0, stream>>>(pS, pS2, G1, BE1, sa1, sb1);
  k_bn1apply<<<(int)(szh1 / 256), 256, 0, stream>>>(H1t, sa1, sb1, H1tb);

  // ---- conv2 (MFMA + fused BN2 partials) + BN2 combine/apply ----
  k_mgemm<2><<<dim3(2, 128, 1), 256, 0, stream>>>(H1tb, 0, DMID, W2b, 0, DMID,
                                                  Hn, 0, DEMB, DMID, B2, pA2, pB2, 0, 0);
  k_bn2b<<<1, 256, 0, stream>>>(pA2, pB2, G2, BE2, sa2, sb2);
  k_bnapply2<<<(int)(BATCH * STRD / 256), 256, 0, stream>>>(Hn, Htb, sa2, sb2);

  // ---- SA layers (batch b pinned to XCD b across the whole chain) ----
  for (int l = 0; l < NSA; ++l) {
    // fused QKt + V projections (one launch, 768 blocks)
    k_qkv<<<dim3(768), 256, 0, stream>>>(Htb, WQKb + (long)l * 512 * DEMB,
                                         WVb + (long)l * DEMB * DEMB, QKt, Vb);
    for (int b0 = 0; b0 < BATCH; b0 += G) {
      // F[m][n] = sum_a Kt[m][a] Qt[n][a] (= E^T), bf16 + fused exact column stats
      k_mgemm<0><<<dim3(256 * G), 256, 0, stream>>>(QKt + 256 + b0 * QKS, QKS, 512,
                                                    QKt + b0 * QKS, QKS, 512,
                                                    F, NN, NPT, DEMB, nullptr, PM, PSm, G, 16);
      // Hn += S*(V.PT); Htb = bf16(Hn) (non-last); last layer: emit POOL only
      k_vp<<<dim3(32 * G), 512, 0, stream>>>(F, PM, PSm, Vb + b0 * STRD,
                                             Hn + b0 * STRD, Htb + b0 * STRD,
                                             POOL + b0 * NPT, G,
                                             (l < NSA - 1) ? 1 : 0);
    }
  }

  // ---- head ----
  k_fc1<<<NPT, 256, 0, stream>>>(POOL, FC1W, FC1B, FH);
  k_fc2<<<BATCH, 256, 0, stream>>>(FH, FC2W, FC2B, OUT);
}

// Round 21
// 369.447 us; speedup vs baseline: 1.1808x; 1.0446x over previous
//
#include <hip/hip_runtime.h>
#include <hip/hip_bf16.h>

typedef __hip_bfloat16 bf16;
#define DEVI __device__ __forceinline__

// Problem constants
static constexpr int BATCH = 8;
static constexpr int NPT   = 2048;
static constexpr int DMID  = 64;
static constexpr int DEMB  = 256;
static constexpr int NSA   = 4;
static constexpr long STRD = (long)DEMB * NPT;  // 524288
static constexpr long QKS  = (long)NPT * 512;   // per-batch stride of QKt
static constexpr long NN   = (long)NPT * NPT;   // 4194304

typedef __attribute__((ext_vector_type(4))) float f32x4;
typedef __attribute__((ext_vector_type(8))) short bf16x8v;

DEVI f32x4 MFMA16(bf16x8v a, bf16x8v b, f32x4 c) {
  return __builtin_amdgcn_mfma_f32_16x16x32_bf16(a, b, c, 0, 0, 0);
}

DEVI void gload16(const bf16* g, bf16* l) {
  __builtin_amdgcn_global_load_lds(
      (const __attribute__((address_space(1))) void*)g,
      (__attribute__((address_space(3))) void*)l, 16, 0, 0);
}

DEVI float waveReduceSum(float v) {
#pragma unroll
  for (int o = 32; o > 0; o >>= 1) v += __shfl_down(v, o, 64);
  return v;
}
DEVI float blockReduceSum(float v) {
  __shared__ float sm[4];
  int lane = threadIdx.x & 63, wid = threadIdx.x >> 6;
  __syncthreads();
  v = waveReduceSum(v);
  if (lane == 0) sm[wid] = v;
  __syncthreads();
  return sm[0] + sm[1] + sm[2] + sm[3];
}

// ---- fused weight converts: W2 | [Wq;Wk] concat | Wv ----
__global__ void k_cvtall(const float* __restrict__ w2, const float* __restrict__ wq,
                         const float* __restrict__ wk, const float* __restrict__ wv,
                         bf16* __restrict__ W2b, bf16* __restrict__ WQKb,
                         bf16* __restrict__ WVb) {
  int idx = blockIdx.x * 256 + threadIdx.x;
  if (idx < DEMB * DMID) {
    W2b[idx] = __float2bfloat16(w2[idx]);
  } else if (idx < DEMB * DMID + NSA * 512 * DEMB) {
    int i = idx - DEMB * DMID;
    int c = i & 255;
    int r = (i >> 8) & 511;
    int l = i >> 17;
    float v = (r < 256) ? wq[((l << 8) + r) * 256 + c] : wk[((l << 8) + (r - 256)) * 256 + c];
    WQKb[i] = __float2bfloat16(v);
  } else {
    int i = idx - (DEMB * DMID + NSA * 512 * DEMB);
    if (i < NSA * DEMB * DEMB) WVb[i] = __float2bfloat16(wv[i]);
  }
}

// ---- fused conv1 + BN1 partial stats ----
// Block handles 128 rows x 64 cols; thread (c, rg) covers rows r0..r0+31
// exactly like the old k_bn1a, with conv computed inline (same fma order).
__global__ __launch_bounds__(256) void k_conv1bn(const float* __restrict__ x,
                                                 const float* __restrict__ w1,
                                                 const float* __restrict__ b1,
                                                 float* __restrict__ h1t,
                                                 float* __restrict__ pS, float* __restrict__ pS2) {
  int c = threadIdx.x & 63, rg = threadIdx.x >> 6;
  long r0 = (long)blockIdx.x * 128 + rg * 32;
  float w0 = w1[c * 3], w1v = w1[c * 3 + 1], w2v = w1[c * 3 + 2], bb = b1[c];
  float s = 0.f, s2 = 0.f;
  for (int i = 0; i < 32; ++i) {
    long r = r0 + i;
    const float* xp = x + r * 3;
    float acc = bb;
    acc += xp[0] * w0;
    acc += xp[1] * w1v;
    acc += xp[2] * w2v;
    h1t[r * 64 + c] = acc;
    s += acc; s2 += acc * acc;
  }
  __shared__ float smS[256], smS2[256];
  smS[threadIdx.x] = s; smS2[threadIdx.x] = s2;
  __syncthreads();
  if (threadIdx.x < 64) {
    float a = 0.f, b = 0.f;
#pragma unroll
    for (int g = 0; g < 4; ++g) { a += smS[g * 64 + c]; b += smS2[g * 64 + c]; }
    pS[blockIdx.x * 64 + c] = a;
    pS2[blockIdx.x * 64 + c] = b;
  }
}
__global__ void k_bn1b(const float* __restrict__ pS, const float* __restrict__ pS2,
                       const float* __restrict__ g, const float* __restrict__ be,
                       float* __restrict__ sa, float* __restrict__ sb) {
  int c = threadIdx.x;
  if (c >= 64) return;
  float s = 0.f, s2 = 0.f;
  for (int i = 0; i < 128; ++i) { s += pS[i * 64 + c]; s2 += pS2[i * 64 + c]; }
  const float inv = 1.0f / (BATCH * NPT);
  float m = s * inv, var = s2 * inv - m * m;
  float A = rsqrtf(var + 1e-5f) * g[c];
  sa[c] = A; sb[c] = be[c] - m * A;
}
// BN1 apply + ReLU (vectorized x4)
__global__ void k_bn1apply(const float* __restrict__ h, const float* __restrict__ sa,
                           const float* __restrict__ sb, bf16* __restrict__ o) {
  long i = ((long)blockIdx.x * 256 + threadIdx.x) * 4;
  int c = (int)(i & 63);
  float4 v4 = *(const float4*)(h + i);
  float4 a4 = *(const float4*)(sa + c);
  float4 b4 = *(const float4*)(sb + c);
  float r0 = fmaf(v4.x, a4.x, b4.x); r0 = r0 > 0.f ? r0 : 0.f;
  float r1 = fmaf(v4.y, a4.y, b4.y); r1 = r1 > 0.f ? r1 : 0.f;
  float r2 = fmaf(v4.z, a4.z, b4.z); r2 = r2 > 0.f ? r2 : 0.f;
  float r3 = fmaf(v4.w, a4.w, b4.w); r3 = r3 > 0.f ? r3 : 0.f;
  bf16 hb[4] = {__float2bfloat16(r0), __float2bfloat16(r1),
                __float2bfloat16(r2), __float2bfloat16(r3)};
  *(uint2*)(o + i) = *(uint2*)hb;
}

// ---- BN2 combine (partials from conv2 epilogue) ----
__global__ void k_bn2b(const float* __restrict__ pA, const float* __restrict__ pB,
                       const float* __restrict__ g, const float* __restrict__ be,
                       float* __restrict__ sa, float* __restrict__ sb) {
  int c = threadIdx.x;  // 256 threads
  float s = 0.f, s2 = 0.f;
  for (int i = 0; i < 128; ++i) { s += pA[i * DEMB + c]; s2 += pB[i * DEMB + c]; }
  const float inv = 1.0f / (BATCH * NPT);
  float m = s * inv, var = s2 * inv - m * m;
  float A = rsqrtf(var + 1e-5f) * g[c];
  sa[c] = A; sb[c] = be[c] - m * A;
}
// BN2 apply + ReLU: write Hn (f32) and Htb (bf16), vectorized x4
__global__ void k_bnapply2(float* __restrict__ hn, bf16* __restrict__ htb,
                           const float* __restrict__ sa, const float* __restrict__ sb) {
  long i = ((long)blockIdx.x * 256 + threadIdx.x) * 4;
  int c = (int)(i & (DEMB - 1));
  float4 v4 = *(const float4*)(hn + i);
  float4 a4 = *(const float4*)(sa + c);
  float4 b4 = *(const float4*)(sb + c);
  float r0 = fmaf(v4.x, a4.x, b4.x); r0 = r0 > 0.f ? r0 : 0.f;
  float r1 = fmaf(v4.y, a4.y, b4.y); r1 = r1 > 0.f ? r1 : 0.f;
  float r2 = fmaf(v4.z, a4.z, b4.z); r2 = r2 > 0.f ? r2 : 0.f;
  float r3 = fmaf(v4.w, a4.w, b4.w); r3 = r3 > 0.f ? r3 : 0.f;
  *(float4*)(hn + i) = float4{r0, r1, r2, r3};
  bf16 hb[4] = {__float2bfloat16(r0), __float2bfloat16(r1),
                __float2bfloat16(r2), __float2bfloat16(r3)};
  *(uint2*)(htb + i) = *(uint2*)hb;
}

// ---- MFMA GEMM (conv2 only now): C f32 = A.B^T + bias[col], fused BN partials ----
__global__ __launch_bounds__(256) void k_mgemm2(
    const bf16* __restrict__ A, int ldA,
    const bf16* __restrict__ B, int ldB,
    float* __restrict__ C, int ldC,
    int K, const float* __restrict__ bias,
    float* __restrict__ PMo, float* __restrict__ PSo) {
  __shared__ __align__(16) bf16 sA[128 * 64];
  __shared__ __align__(16) bf16 sB[128 * 64];
  __shared__ float smx[4][64], ssx[4][64];
  const int bx = blockIdx.x, by = blockIdx.y;
  const int bm = by * 128, bn = bx * 128;
  const int tid = threadIdx.x;
  const int lane = tid & 63, wv = tid >> 6;
  const int wr = (wv >> 1) * 64, wc = (wv & 1) * 64;
  f32x4 acc[4][4] = {};

  for (int k0 = 0; k0 < K; k0 += 64) {
#pragma unroll
    for (int i = 0; i < 4; ++i) {
      int c = i * 256 + tid;
      int row = c >> 3, g = c & 7;
      int gs = (g ^ (row & 7)) * 8;
      gload16(A + (long)(bm + row) * ldA + k0 + gs, sA + c * 8);
      gload16(B + (long)(bn + row) * ldB + k0 + gs, sB + c * 8);
    }
    __syncthreads();
    bf16x8v af[4][2], bfr[4][2];
#pragma unroll
    for (int mi = 0; mi < 4; ++mi)
#pragma unroll
      for (int ks = 0; ks < 2; ++ks) {
        int rA = wr + mi * 16 + (lane & 15);
        int rB = wc + mi * 16 + (lane & 15);
        int g = ks * 4 + (lane >> 4);
        af[mi][ks]  = *(const bf16x8v*)&sA[rA * 64 + ((g ^ (rA & 7)) * 8)];
        bfr[mi][ks] = *(const bf16x8v*)&sB[rB * 64 + ((g ^ (rB & 7)) * 8)];
      }
#pragma unroll
    for (int ks = 0; ks < 2; ++ks)
#pragma unroll
      for (int mi = 0; mi < 4; ++mi)
#pragma unroll
        for (int ni = 0; ni < 4; ++ni)
          acc[mi][ni] = MFMA16(af[mi][ks], bfr[ni][ks], acc[mi][ni]);
    __syncthreads();
  }

  const int rb = (lane >> 4) * 4, cb = lane & 15;
  float st_s[4] = {}, st_q[4] = {};
#pragma unroll
  for (int mi = 0; mi < 4; ++mi)
#pragma unroll
    for (int ni = 0; ni < 4; ++ni) {
      int r0 = bm + wr + mi * 16 + rb, c0 = bn + wc + ni * 16 + cb;
      float badd = bias[c0];
#pragma unroll
      for (int k = 0; k < 4; ++k) {
        int r = r0 + k;
        float v = acc[mi][ni][k] + badd;
        C[(long)r * ldC + c0] = v;
        st_s[ni] += v;
        st_q[ni] += v * v;
      }
    }

#pragma unroll
  for (int ni = 0; ni < 4; ++ni) {
#pragma unroll
    for (int off = 16; off <= 32; off <<= 1) {
      st_s[ni] += __shfl_xor(st_s[ni], off, 64);
      st_q[ni] += __shfl_xor(st_q[ni], off, 64);
    }
  }
  __syncthreads();
  if (lane < 16) {
#pragma unroll
    for (int ni = 0; ni < 4; ++ni) {
      smx[wv][ni * 16 + lane] = st_s[ni];
      ssx[wv][ni * 16 + lane] = st_q[ni];
    }
  }
  __syncthreads();
  if (tid < 128) {
    int half = tid >> 6, c64 = tid & 63;
    float S = smx[half][c64] + smx[half + 2][c64];
    float Q = ssx[half][c64] + ssx[half + 2][c64];
    int col = bn + half * 64 + c64;
    PMo[by * DEMB + col] = S;
    PSo[by * DEMB + col] = Q;
  }
}

// ---- QKt projection only: QKt[z][n][0..511] = Htb[z] . WQK^T ----
__global__ __launch_bounds__(256) void k_qk(
    const bf16* __restrict__ Htb, const bf16* __restrict__ WQK, bf16* __restrict__ QKt) {
  __shared__ __align__(16) bf16 sA[128 * 64];
  __shared__ __align__(16) bf16 sB[128 * 64];
  int s = blockIdx.x;
  int z = s & 7, t = s >> 3;
  const bf16* A = Htb + (long)z * STRD;
  const bf16* B = WQK;
  bf16* C = QKt + (long)z * QKS;
  const int bm = (t >> 2) * 128, bn = (t & 3) * 128;
  const int tid = threadIdx.x;
  const int lane = tid & 63, wv = tid >> 6;
  const int wr = (wv >> 1) * 64, wc = (wv & 1) * 64;
  f32x4 acc[4][4] = {};

  for (int k0 = 0; k0 < DEMB; k0 += 64) {
#pragma unroll
    for (int i = 0; i < 4; ++i) {
      int c = i * 256 + tid;
      int row = c >> 3, g = c & 7;
      int gs = (g ^ (row & 7)) * 8;
      gload16(A + (long)(bm + row) * DEMB + k0 + gs, sA + c * 8);
      gload16(B + (long)(bn + row) * DEMB + k0 + gs, sB + c * 8);
    }
    __syncthreads();
    bf16x8v af[4][2], bfr[4][2];
#pragma unroll
    for (int mi = 0; mi < 4; ++mi)
#pragma unroll
      for (int ks = 0; ks < 2; ++ks) {
        int rA = wr + mi * 16 + (lane & 15);
        int rB = wc + mi * 16 + (lane & 15);
        int g = ks * 4 + (lane >> 4);
        af[mi][ks]  = *(const bf16x8v*)&sA[rA * 64 + ((g ^ (rA & 7)) * 8)];
        bfr[mi][ks] = *(const bf16x8v*)&sB[rB * 64 + ((g ^ (rB & 7)) * 8)];
      }
#pragma unroll
    for (int ks = 0; ks < 2; ++ks)
#pragma unroll
      for (int mi = 0; mi < 4; ++mi)
#pragma unroll
        for (int ni = 0; ni < 4; ++ni)
          acc[mi][ni] = MFMA16(af[mi][ks], bfr[ni][ks], acc[mi][ni]);
    __syncthreads();
  }

  const int rb = (lane >> 4) * 4, cb = lane & 15;
#pragma unroll
  for (int mi = 0; mi < 4; ++mi)
#pragma unroll
    for (int ni = 0; ni < 4; ++ni) {
      int r0 = bm + wr + mi * 16 + rb, c0 = bn + wc + ni * 16 + cb;
#pragma unroll
      for (int k = 0; k < 4; ++k)
        C[(long)(r0 + k) * 512 + c0] = __float2bfloat16(acc[mi][ni][k]);
    }
}

// ---- merged F-GEMM + V-projection (one launch; V overlaps F) ----
// Slots [0, 256*G): F[m][n] = sum_a Kt[m][a] Qt[n][a] (bf16) + column stats
// Slots [256*G, 288*G): Vb[z][e][n] = WV . Htb[z]^T
__global__ __launch_bounds__(256) void k_fv(
    const bf16* __restrict__ QKt0, const bf16* __restrict__ WV,
    const bf16* __restrict__ Htb0, bf16* __restrict__ F, bf16* __restrict__ Vb0,
    float* __restrict__ PMo, float* __restrict__ PSo, int G) {
  __shared__ __align__(16) bf16 sA[128 * 64];
  __shared__ __align__(16) bf16 sB[128 * 64];
  __shared__ float smx[4][64], ssx[4][64];
  const bf16 *A, *B;
  bf16* C;
  int ldA, ldB, ldC, bm, bn, by, bz;
  bool isF;
  {
    int s = blockIdx.x;
    isF = s < 256 * G;
    if (isF) {
      bz = s % G;
      int t = s / G;
      int bx = t & 15;
      by = t >> 4;
      A = QKt0 + 256 + (long)bz * QKS; ldA = 512;
      B = QKt0 + (long)bz * QKS;       ldB = 512;
      C = F + (long)bz * NN;           ldC = NPT;
      bm = by * 128; bn = bx * 128;
    } else {
      int s2 = s - 256 * G;
      bz = s2 % G;
      int t = s2 / G;
      A = WV;                          ldA = DEMB;
      B = Htb0 + (long)bz * STRD;      ldB = DEMB;
      C = Vb0 + (long)bz * STRD;       ldC = NPT;
      bm = (t >> 4) * 128; bn = (t & 15) * 128;
      by = 0;
    }
  }
  const int tid = threadIdx.x;
  const int lane = tid & 63, wv = tid >> 6;
  const int wr = (wv >> 1) * 64, wc = (wv & 1) * 64;
  f32x4 acc[4][4] = {};

  for (int k0 = 0; k0 < DEMB; k0 += 64) {
#pragma unroll
    for (int i = 0; i < 4; ++i) {
      int c = i * 256 + tid;
      int row = c >> 3, g = c & 7;
      int gs = (g ^ (row & 7)) * 8;
      gload16(A + (long)(bm + row) * ldA + k0 + gs, sA + c * 8);
      gload16(B + (long)(bn + row) * ldB + k0 + gs, sB + c * 8);
    }
    __syncthreads();
    bf16x8v af[4][2], bfr[4][2];
#pragma unroll
    for (int mi = 0; mi < 4; ++mi)
#pragma unroll
      for (int ks = 0; ks < 2; ++ks) {
        int rA = wr + mi * 16 + (lane & 15);
        int rB = wc + mi * 16 + (lane & 15);
        int g = ks * 4 + (lane >> 4);
        af[mi][ks]  = *(const bf16x8v*)&sA[rA * 64 + ((g ^ (rA & 7)) * 8)];
        bfr[mi][ks] = *(const bf16x8v*)&sB[rB * 64 + ((g ^ (rB & 7)) * 8)];
      }
#pragma unroll
    for (int ks = 0; ks < 2; ++ks)
#pragma unroll
      for (int mi = 0; mi < 4; ++mi)
#pragma unroll
        for (int ni = 0; ni < 4; ++ni)
          acc[mi][ni] = MFMA16(af[mi][ks], bfr[ni][ks], acc[mi][ni]);
    __syncthreads();
  }

  const int rb = (lane >> 4) * 4, cb = lane & 15;
#pragma unroll
  for (int mi = 0; mi < 4; ++mi)
#pragma unroll
    for (int ni = 0; ni < 4; ++ni) {
      int r0 = bm + wr + mi * 16 + rb, c0 = bn + wc + ni * 16 + cb;
#pragma unroll
      for (int k = 0; k < 4; ++k)
        C[(long)(r0 + k) * ldC + c0] = __float2bfloat16(acc[mi][ni][k]);
    }

  if (isF) {
    // per-column (over this block's 128 rows) online-softmax partials
    float cm[4], cs[4];
#pragma unroll
    for (int ni = 0; ni < 4; ++ni) {
      float m = -3.0e38f;
#pragma unroll
      for (int mi = 0; mi < 4; ++mi)
#pragma unroll
        for (int k = 0; k < 4; ++k) m = fmaxf(m, acc[mi][ni][k]);
      float s = 0.f;
#pragma unroll
      for (int mi = 0; mi < 4; ++mi)
#pragma unroll
        for (int k = 0; k < 4; ++k) s += __expf(acc[mi][ni][k] - m);
#pragma unroll
      for (int off = 16; off <= 32; off <<= 1) {
        float mo = __shfl_xor(m, off, 64);
        float so = __shfl_xor(s, off, 64);
        float M = fmaxf(m, mo);
        s = s * __expf(m - M) + so * __expf(mo - M);
        m = M;
      }
      cm[ni] = m; cs[ni] = s;
    }
    __syncthreads();
    if (lane < 16) {
#pragma unroll
      for (int ni = 0; ni < 4; ++ni) {
        smx[wv][ni * 16 + lane] = cm[ni];
        ssx[wv][ni * 16 + lane] = cs[ni];
      }
    }
    __syncthreads();
    if (tid < 128) {
      int half = tid >> 6, c64 = tid & 63;
      float m1 = smx[half][c64], s1 = ssx[half][c64];
      float m2 = smx[half + 2][c64], s2 = ssx[half + 2][c64];
      float M = fmaxf(m1, m2);
      float S = s1 * __expf(m1 - M) + s2 * __expf(m2 - M);
      long o = ((long)bz * 16 + by) * NPT + bn + half * 64 + c64;
      PMo[o] = M;
      PSo[o] = S;
    }
  }
}

// ---- fused colstat-combine + normalize + rowsum + V.P GEMM ----
// wHtb=1: Hn += delta, Htb = bf16(Hn). wHtb=0 (last layer): no Hn/Htb
// writes; instead POOL[z*NPT + m] = rowmean_e(Hn + delta).
__global__ __launch_bounds__(512) void k_vp(const bf16* __restrict__ F,
                                            const float* __restrict__ PM,
                                            const float* __restrict__ PSm,
                                            const bf16* __restrict__ V,
                                            float* __restrict__ Hn,
                                            bf16* __restrict__ Htb,
                                            float* __restrict__ POOL, int nz, int wHtb) {
  __shared__ __align__(16) bf16 sA[2][256 * 64];
  __shared__ __align__(16) bf16 sB[2][64 * 64];
  __shared__ float rsLds[64][8];
  __shared__ float Sv[64];
  __shared__ float psum[8][32];
  __shared__ float smCM[NPT], smCS[NPT];
  const int z = blockIdx.x % nz;
  const int m0 = (blockIdx.x / nz) * 64;
  const int tid = threadIdx.x;
  const int lane = tid & 63, wv = tid >> 6;
  const int we = wv & 3;
  const int wm = wv >> 2;
  const int fr = tid >> 3;
  const int fq = tid & 7;
  const bf16* Vz = V + (long)z * STRD;
  const bf16* Frp = F + (long)z * NN + (long)(m0 + fr) * NPT + fq * 8;
  f32x4 acc[4][2] = {};
  float rs = 0.f;
  bf16x8v fvA, fvB;

  {
    const float* pm = PM + (long)z * 16 * NPT;
    const float* ps = PSm + (long)z * 16 * NPT;
#pragma unroll
    for (int i = 0; i < 4; ++i) {
      int n = i * 512 + tid;
      float m = -3.0e38f;
#pragma unroll
      for (int y = 0; y < 16; ++y) m = fmaxf(m, pm[(long)y * NPT + n]);
      float s = 0.f;
#pragma unroll
      for (int y = 0; y < 16; ++y) s += ps[(long)y * NPT + n] * __expf(pm[(long)y * NPT + n] - m);
      smCM[n] = m;
      smCS[n] = 1.0f / s;
    }
  }

#define LOADF(FREG, N0) FREG = *(const bf16x8v*)(Frp + ((N0) & 2047));

#define EXPW(BUF, FREG, N0)                                                    \
  {                                                                            \
    float mv[8], cv[8];                                                        \
    *(float4*)&mv[0] = *(const float4*)&smCM[(N0) + fq * 8];                   \
    *(float4*)&mv[4] = *(const float4*)&smCM[(N0) + fq * 8 + 4];               \
    *(float4*)&cv[0] = *(const float4*)&smCS[(N0) + fq * 8];                   \
    *(float4*)&cv[4] = *(const float4*)&smCS[(N0) + fq * 8 + 4];               \
    bf16 tb[8];                                                                \
    _Pragma("unroll") for (int i = 0; i < 8; ++i) {                            \
      float fvi = __uint_as_float((unsigned)(unsigned short)FREG[i] << 16);    \
      float pv = __expf(fvi - mv[i]) * cv[i];                                  \
      rs += pv;                                                                \
      tb[i] = __float2bfloat16(pv);                                            \
    }                                                                          \
    *(bf16x8v*)&sB[BUF][fr * 64 + ((fq ^ (fr & 7)) * 8)] = *(bf16x8v*)tb;      \
  }

#define STAGEV(BUF, N0)                                                        \
  _Pragma("unroll") for (int i = 0; i < 4; ++i) {                              \
    int c = i * 512 + tid;                                                     \
    int row = c >> 3, g = c & 7;                                               \
    gload16(Vz + (long)row * NPT + ((N0) & 2047) + ((g ^ (row & 7)) * 8),      \
            &sA[BUF][c * 8]);                                                  \
  }

#define WAITBAR                                                                \
  asm volatile("s_waitcnt vmcnt(1) lgkmcnt(0)" ::: "memory");                  \
  __builtin_amdgcn_s_barrier();

  LOADF(fvA, 0)
  STAGEV(0, 0)
  __syncthreads();
  EXPW(0, fvA, 0)
  LOADF(fvB, 64)
  __syncthreads();

#define VP_BODY(CUR, FN, FN2, STEPI)                                           \
  {                                                                            \
    const int sn = (STEPI);                                                    \
    const int nn0 = sn * 64;                                                   \
    STAGEV(CUR ^ 1, nn0 + 64)                                                  \
    LOADF(FN2, nn0 + 128)                                                      \
    if (sn + 1 < 32) EXPW(CUR ^ 1, FN, nn0 + 64)                               \
    bf16x8v bfr[2][2];                                                         \
    _Pragma("unroll") for (int ni = 0; ni < 2; ++ni)                           \
      _Pragma("unroll") for (int ks = 0; ks < 2; ++ks) {                       \
        int rB = wm * 32 + ni * 16 + (lane & 15);                              \
        int g = ks * 4 + (lane >> 4);                                          \
        bfr[ni][ks] = *(const bf16x8v*)&sB[CUR][rB * 64 + ((g ^ (rB & 7)) * 8)]; \
      }                                                                        \
    _Pragma("unroll") for (int mi = 0; mi < 4; ++mi)                           \
      _Pragma("unroll") for (int ks = 0; ks < 2; ++ks) {                       \
        int rA = we * 64 + mi * 16 + (lane & 15);                              \
        int g = ks * 4 + (lane >> 4);                                          \
        bf16x8v af = *(const bf16x8v*)&sA[CUR][rA * 64 + ((g ^ (rA & 7)) * 8)]; \
        _Pragma("unroll") for (int ni = 0; ni < 2; ++ni)                       \
          acc[mi][ni] = MFMA16(af, bfr[ni][ks], acc[mi][ni]);                  \
      }                                                                        \
    WAITBAR                                                                    \
  }

  for (int it = 0; it < 16; ++it) {
    VP_BODY(0, fvB, fvA, 2 * it)
    VP_BODY(1, fvA, fvB, 2 * it + 1)
  }
#undef VP_BODY
#undef WAITBAR
#undef STAGEV
#undef EXPW
#undef LOADF

  rsLds[fr][fq] = rs;
  __syncthreads();
  if (tid < 64) {
    float R = 0.f;
#pragma unroll
    for (int q = 0; q < 8; ++q) R += rsLds[tid][q];
    Sv[tid] = 1.0f / (1e-9f + R);
  }
  __syncthreads();

  float* Hz = Hn + (long)z * STRD;
  bf16* Hb = Htb + (long)z * STRD;
  const int rb = (lane >> 4) * 4, cb = lane & 15;
  float csum[2] = {0.f, 0.f};
#pragma unroll
  for (int mi = 0; mi < 4; ++mi) {
    int e0 = we * 64 + mi * 16 + rb;
#pragma unroll
    for (int ni = 0; ni < 2; ++ni) {
      int c = wm * 32 + ni * 16 + cb;
      float scl = Sv[c];
      long base = (long)(m0 + c) * DEMB + e0;
      float4 h = *(const float4*)(Hz + base);
      float r0 = h.x + acc[mi][ni][0] * scl;
      float r1 = h.y + acc[mi][ni][1] * scl;
      float r2 = h.z + acc[mi][ni][2] * scl;
      float r3 = h.w + acc[mi][ni][3] * scl;
      if (wHtb) {
        *(float4*)(Hz + base) = float4{r0, r1, r2, r3};
        bf16 hb[4] = {__float2bfloat16(r0), __float2bfloat16(r1),
                      __float2bfloat16(r2), __float2bfloat16(r3)};
        *(uint2*)(Hb + base) = *(uint2*)hb;
      }
      csum[ni] += (r0 + r1) + (r2 + r3);
    }
  }

  if (!wHtb) {
#pragma unroll
    for (int ni = 0; ni < 2; ++ni) {
      float s = csum[ni];
      s += __shfl_down(s, 16, 64);
      s += __shfl_down(s, 32, 64);
      if (lane < 16) psum[wv][ni * 16 + lane] = s;
    }
    __syncthreads();
    if (tid < 64) {
      int wmq = tid >> 5, cl = tid & 31;
      float s = psum[wmq * 4 + 0][cl] + psum[wmq * 4 + 1][cl] +
                psum[wmq * 4 + 2][cl] + psum[wmq * 4 + 3][cl];
      POOL[(long)z * NPT + m0 + wmq * 32 + cl] = s * (1.0f / DEMB);
    }
  }
}

// ---- fc1: one block per output row j; w row read ONCE, all 8 batches ----
__global__ __launch_bounds__(256) void k_fc1(const float* __restrict__ pooled,
                                             const float* __restrict__ w, const float* __restrict__ bias,
                                             float* __restrict__ f) {
  int j = blockIdx.x;
  const float* wr = w + (long)j * NPT;
  int n0 = threadIdx.x * 8;
  float wl[8];
  *(float4*)&wl[0] = *(const float4*)(wr + n0);
  *(float4*)&wl[4] = *(const float4*)(wr + n0 + 4);
  float part[8];
#pragma unroll
  for (int b = 0; b < 8; ++b) {
    const float* pp = pooled + (long)b * NPT + n0;
    float4 p0 = *(const float4*)pp, p1 = *(const float4*)(pp + 4);
    part[b] = wl[0] * p0.x + wl[1] * p0.y + wl[2] * p0.z + wl[3] * p0.w +
              wl[4] * p1.x + wl[5] * p1.y + wl[6] * p1.z + wl[7] * p1.w;
  }
#pragma unroll
  for (int b = 0; b < 8; ++b) {
    float s = blockReduceSum(part[b]);
    if (threadIdx.x == 0) {
      s += bias[j];
      f[(long)b * NPT + j] = s > 0.f ? s : 0.f;
    }
  }
}

// ---- fc2 ----
__global__ __launch_bounds__(256) void k_fc2(const float* __restrict__ f,
                                             const float* __restrict__ w, const float* __restrict__ bias,
                                             float* __restrict__ out) {
  int b = blockIdx.x;
  float s = 0.f;
  for (int j = threadIdx.x; j < NPT; j += 256) s += f[(long)b * NPT + j] * w[j];
  s = blockReduceSum(s);
  if (threadIdx.x == 0) out[b] = s + bias[0];
}

extern "C" void kernel_launch(void* const* d_in, const int* in_sizes, int n_in,
                              void* d_out, int out_size, void* d_ws, size_t ws_size,
                              hipStream_t stream) {
  const float* X    = (const float*)d_in[0];
  const float* W1   = (const float*)d_in[1];
  const float* B1   = (const float*)d_in[2];
  const float* G1   = (const float*)d_in[3];
  const float* BE1  = (const float*)d_in[4];
  const float* W2   = (const float*)d_in[5];
  const float* B2   = (const float*)d_in[6];
  const float* G2   = (const float*)d_in[7];
  const float* BE2  = (const float*)d_in[8];
  const float* WQ   = (const float*)d_in[9];
  const float* WK   = (const float*)d_in[10];
  const float* WV   = (const float*)d_in[11];
  const float* FC1W = (const float*)d_in[12];
  const float* FC1B = (const float*)d_in[13];
  const float* FC2W = (const float*)d_in[14];
  const float* FC2B = (const float*)d_in[15];
  float* OUT = (float*)d_out;

  // ---- workspace carve-out ----
  char* p = (char*)d_ws;
  auto alloc = [&](size_t bytes) -> char* {
    char* r = p;
    p += (bytes + 255) & ~(size_t)255;
    return r;
  };
  float* H1t  = (float*)alloc((size_t)BATCH * NPT * DMID * 4);
  bf16*  H1tb = (bf16*)alloc((size_t)BATCH * NPT * DMID * 2);
  float* Hn   = (float*)alloc((size_t)BATCH * STRD * 4);   // [b*n][256] f32
  bf16*  Htb  = (bf16*)alloc((size_t)BATCH * STRD * 2);    // [b*n][256] bf16
  bf16*  QKt  = (bf16*)alloc((size_t)BATCH * QKS * 2);     // [b][n][512]
  bf16*  Vb   = (bf16*)alloc((size_t)BATCH * STRD * 2);    // [b][e][n]
  bf16*  W2b  = (bf16*)alloc((size_t)DEMB * DMID * 2);
  bf16*  WQKb = (bf16*)alloc((size_t)NSA * 512 * DEMB * 2);
  bf16*  WVb  = (bf16*)alloc((size_t)NSA * DEMB * DEMB * 2);
  float* pS   = (float*)alloc(128 * 64 * 4);
  float* pS2  = (float*)alloc(128 * 64 * 4);
  float* pA2  = (float*)alloc(128 * DEMB * 4);
  float* pB2  = (float*)alloc(128 * DEMB * 4);
  float* sa1  = (float*)alloc(64 * 4);
  float* sb1  = (float*)alloc(64 * 4);
  float* sa2  = (float*)alloc(256 * 4);
  float* sb2  = (float*)alloc(256 * 4);
  float* PM   = (float*)alloc((size_t)BATCH * 16 * NPT * 4);
  float* PSm  = (float*)alloc((size_t)BATCH * 16 * NPT * 4);
  float* POOL = (float*)alloc((size_t)BATCH * NPT * 4);
  float* FH   = (float*)alloc((size_t)BATCH * NPT * 4);
  size_t used = (size_t)(p - (char*)d_ws);
  const size_t per_g = (size_t)NN * 2;  // F bf16 (8MB per batch)
  int G = 8;
  while (G > 1 && used + (size_t)G * per_g + 1024 > ws_size) G >>= 1;
  bf16* F = (bf16*)alloc((size_t)G * NN * 2);

  // ---- fused weight converts (one launch) ----
  int ncv = DEMB * DMID + NSA * 512 * DEMB + NSA * DEMB * DEMB;
  k_cvtall<<<(ncv + 255) / 256, 256, 0, stream>>>(W2, WQ, WK, WV, W2b, WQKb, WVb);

  // ---- conv1 (+fused BN1 partials) + BN1 combine/apply ----
  k_conv1bn<<<128, 256, 0, stream>>>(X, W1, B1, H1t, pS, pS2);
  k_bn1b<<<1, 64, 0, stream>>>(pS, pS2, G1, BE1, sa1, sb1);
  k_bn1apply<<<(int)((long)BATCH * NPT * DMID / 4 / 256), 256, 0, stream>>>(H1t, sa1, sb1, H1tb);

  // ---- conv2 (MFMA + fused BN2 partials) + BN2 combine/apply ----
  k_mgemm2<<<dim3(2, 128), 256, 0, stream>>>(H1tb, DMID, W2b, DMID, Hn, DEMB, DMID,
                                             B2, pA2, pB2);
  k_bn2b<<<1, 256, 0, stream>>>(pA2, pB2, G2, BE2, sa2, sb2);
  k_bnapply2<<<(int)(BATCH * STRD / 4 / 256), 256, 0, stream>>>(Hn, Htb, sa2, sb2);

  // ---- SA layers (batch b pinned to XCD b across the whole chain) ----
  for (int l = 0; l < NSA; ++l) {
    // QKt projection (512 blocks)
    k_qk<<<dim3(512), 256, 0, stream>>>(Htb, WQKb + (long)l * 512 * DEMB, QKt);
    for (int b0 = 0; b0 < BATCH; b0 += G) {
      // F + column stats, with V-projection overlapped in the same launch
      k_fv<<<dim3(288 * G), 256, 0, stream>>>(QKt + b0 * QKS,
                                              WVb + (long)l * DEMB * DEMB,
                                              Htb + b0 * STRD,
                                              F, Vb + b0 * STRD, PM, PSm, G);
      // Hn += S*(V.PT); Htb = bf16(Hn) (non-last); last layer: emit POOL only
      k_vp<<<dim3(32 * G), 512, 0, stream>>>(F, PM, PSm, Vb + b0 * STRD,
                                             Hn + b0 * STRD, Htb + b0 * STRD,
                                             POOL + b0 * NPT, G,
                                             (l < NSA - 1) ? 1 : 0);
    }
  }

  // ---- head ----
  k_fc1<<<NPT, 256, 0, stream>>>(POOL, FC1W, FC1B, FH);
  k_fc2<<<BATCH, 256, 0, stream>>>(FH, FC2W, FC2B, OUT);
}